// Round 12
// baseline (864.996 us; speedup 1.0000x reference)
//
#include <hip/hip_runtime.h>
#include <hip/hip_bf16.h>
#include <math.h>

#define TPB 256

constexpr int Bc = 2, Tc = 2048, Ec = 1024, QKVc = 1024, Hc = 16, DHc = 64;
constexpr long BT = (long)Bc * Tc;     // 4096
constexpr int WR = 5 * QKVc + Ec;      // 6144
constexpr float F32_EPS = 1.1920928955078125e-07f;
constexpr int NCH = 64, CHL = Tc / NCH;

typedef __attribute__((ext_vector_type(8))) short short8;
typedef __attribute__((ext_vector_type(4))) float f32x4;

__device__ __forceinline__ unsigned short f2bu(float f) {
    union { __hip_bfloat16 h; unsigned short u; } c; c.h = __float2bfloat16(f); return c.u;
}
__device__ __forceinline__ float bu2f(unsigned short u) {
    union { __hip_bfloat16 h; unsigned short u; } c; c.u = u; return __bfloat162float(c.h);
}
__device__ __forceinline__ float ldval(const float* p) { return *p; }
__device__ __forceinline__ float ldval(const unsigned short* p) { return bu2f(*p); }

__device__ __forceinline__ void gload_lds16(const void* g, void* l) {
    __builtin_amdgcn_global_load_lds((const __attribute__((address_space(1))) void*)g,
                                     (__attribute__((address_space(3))) void*)l, 16, 0, 0);
}

// ---- DPP cross-lane (VALU pipe): reduce over 16-lane groups ----
template<int CTRL>
__device__ __forceinline__ float dppf(float x) {
    union { float f; int i; } a, b;
    a.f = x;
    b.i = __builtin_amdgcn_update_dpp(0, a.i, CTRL, 0xF, 0xF, true);
    return b.f;
}
__device__ __forceinline__ float max16(float v) {
    v = fmaxf(v, dppf<0xB1>(v));    // quad_perm xor1
    v = fmaxf(v, dppf<0x4E>(v));    // quad_perm xor2
    v = fmaxf(v, dppf<0x124>(v));   // row_ror:4
    v = fmaxf(v, dppf<0x128>(v));   // row_ror:8
    return v;
}
__device__ __forceinline__ float sum16(float v) {
    v += dppf<0xB1>(v);
    v += dppf<0x4E>(v);
    v += dppf<0x124>(v);
    v += dppf<0x128>(v);
    return v;
}

// ---------------- fused 3-segment global std (ddof=1) for w_qkv/w_sw/w_out ----------------
__global__ void k_std_partial3(const float* __restrict__ w, float* __restrict__ out) {
    __shared__ float ls[TPB], lss[TPB];
    int seg = blockIdx.y;
    long base = (seg == 0) ? 0L : (seg == 1 ? 3072L * 1024 : 5120L * 1024);
    long n    = (seg == 0) ? 3072L * 1024 : (seg == 1 ? 2048L * 1024 : 1024L * 1024);
    const float* p = w + base;
    float s = 0.f, ss = 0.f;
    for (long i = (long)blockIdx.x * TPB + threadIdx.x; i < n; i += 256L * TPB) {
        float v = p[i]; s += v; ss += v * v;
    }
    ls[threadIdx.x] = s; lss[threadIdx.x] = ss; __syncthreads();
    for (int o = 128; o > 0; o >>= 1) {
        if (threadIdx.x < o) { ls[threadIdx.x] += ls[threadIdx.x + o]; lss[threadIdx.x] += lss[threadIdx.x + o]; }
        __syncthreads();
    }
    if (threadIdx.x == 0) { out[seg * 512 + blockIdx.x] = ls[0]; out[seg * 512 + 256 + blockIdx.x] = lss[0]; }
}

__global__ void k_std_final3(const float* __restrict__ part, float* __restrict__ scales) {
    __shared__ float ls[TPB], lss[TPB];
    for (int seg = 0; seg < 3; ++seg) {
        ls[threadIdx.x] = part[seg * 512 + threadIdx.x];
        lss[threadIdx.x] = part[seg * 512 + 256 + threadIdx.x];
        __syncthreads();
        for (int o = 128; o > 0; o >>= 1) {
            if (threadIdx.x < o) { ls[threadIdx.x] += ls[threadIdx.x + o]; lss[threadIdx.x] += lss[threadIdx.x + o]; }
            __syncthreads();
        }
        if (threadIdx.x == 0) {
            float n = (seg == 0) ? 3145728.0f : (seg == 1 ? 2097152.0f : 1048576.0f);
            float var = (lss[0] - ls[0] * ls[0] / n) / (n - 1.0f);
            scales[seg] = 0.03125f / (sqrtf(fmaxf(var, 0.0f)) + 1e-8f);
        }
        __syncthreads();
    }
}

// ---------------- generic global std (for w_tmp) ----------------
__global__ void k_std_partial(const float* __restrict__ p, long n, float* __restrict__ out) {
    __shared__ float ls[TPB], lss[TPB];
    float s = 0.f, ss = 0.f;
    for (long i = (long)blockIdx.x * TPB + threadIdx.x; i < n; i += (long)gridDim.x * TPB) {
        float v = p[i]; s += v; ss += v * v;
    }
    ls[threadIdx.x] = s; lss[threadIdx.x] = ss; __syncthreads();
    for (int o = 128; o > 0; o >>= 1) {
        if (threadIdx.x < o) { ls[threadIdx.x] += ls[threadIdx.x + o]; lss[threadIdx.x] += lss[threadIdx.x + o]; }
        __syncthreads();
    }
    if (threadIdx.x == 0) { out[blockIdx.x] = ls[0]; out[gridDim.x + blockIdx.x] = lss[0]; }
}

__global__ void k_std_final(const float* __restrict__ part, float n, float rs, float* __restrict__ scale) {
    __shared__ float ls[TPB], lss[TPB];
    ls[threadIdx.x] = part[threadIdx.x];
    lss[threadIdx.x] = part[TPB + threadIdx.x];
    __syncthreads();
    for (int o = 128; o > 0; o >>= 1) {
        if (threadIdx.x < o) { ls[threadIdx.x] += ls[threadIdx.x + o]; lss[threadIdx.x] += lss[threadIdx.x + o]; }
        __syncthreads();
    }
    if (threadIdx.x == 0) {
        float var = (lss[0] - ls[0] * ls[0] / n) / (n - 1.0f);
        scale[0] = rs / (sqrtf(fmaxf(var, 0.0f)) + 1e-8f);
    }
}

// ---------------- in-place rmsnorm of q and k halves of bf16 qkv (grid 8192) ----------------
__global__ void k_rms_qk(unsigned short* __restrict__ qkv) {
    __shared__ float red[TPB];
    int bid = blockIdx.x;
    long row = bid >> 1; int half = bid & 1;
    unsigned short* p = qkv + row * 3072 + half * 1024;
    ushort4 v = *(const ushort4*)(p + threadIdx.x * 4);
    float f0 = bu2f(v.x), f1 = bu2f(v.y), f2 = bu2f(v.z), f3 = bu2f(v.w);
    red[threadIdx.x] = f0 * f0 + f1 * f1 + f2 * f2 + f3 * f3;
    __syncthreads();
    for (int o = 128; o > 0; o >>= 1) {
        if (threadIdx.x < o) red[threadIdx.x] += red[threadIdx.x + o];
        __syncthreads();
    }
    float sc = rsqrtf(red[0] / 1024.0f + F32_EPS);
    ushort4 o4; o4.x = f2bu(f0 * sc); o4.y = f2bu(f1 * sc); o4.z = f2bu(f2 * sc); o4.w = f2bu(f3 * sc);
    *(ushort4*)(p + threadIdx.x * 4) = o4;
}

// ---------------- rmsnorm over 1024 cols, fp32 in -> bf16 out ----------------
__global__ void k_rms1024b(const float* __restrict__ in, unsigned short* __restrict__ out, long ldin, long ldout) {
    __shared__ float red[TPB];
    long row = blockIdx.x;
    float4 v = *(const float4*)(in + row * ldin + threadIdx.x * 4);
    float ss = v.x * v.x + v.y * v.y + v.z * v.z + v.w * v.w;
    red[threadIdx.x] = ss; __syncthreads();
    for (int o = 128; o > 0; o >>= 1) {
        if (threadIdx.x < o) red[threadIdx.x] += red[threadIdx.x + o];
        __syncthreads();
    }
    float sc = rsqrtf(red[0] / 1024.0f + F32_EPS);
    ushort4 o4; o4.x = f2bu(v.x * sc); o4.y = f2bu(v.y * sc); o4.z = f2bu(v.z * sc); o4.w = f2bu(v.w * sc);
    *(ushort4*)(out + row * ldout + threadIdx.x * 4) = o4;
}

// ---------------- fp32 -> bf16 cast ----------------
__global__ void k_cast_bf16(const float* __restrict__ in, unsigned short* __restrict__ out, long n4) {
    long i = (long)blockIdx.x * TPB + threadIdx.x;
    if (i >= n4) return;
    float4 v = *(const float4*)(in + i * 4);
    ushort4 o; o.x = f2bu(v.x); o.y = f2bu(v.y); o.z = f2bu(v.z); o.w = f2bu(v.w);
    *(ushort4*)(out + i * 4) = o;
}

// ---------------- merge 2 bf16 split-K slabs -> fp32 (+opt residual) ----------------
__global__ void k_merge2(const unsigned short* __restrict__ p0, const unsigned short* __restrict__ p1,
                         const float* __restrict__ resid, float* __restrict__ outp, long n4) {
    long i = (long)blockIdx.x * TPB + threadIdx.x;
    if (i >= n4) return;
    ushort4 a = *(const ushort4*)(p0 + i * 4);
    ushort4 b = *(const ushort4*)(p1 + i * 4);
    float4 o;
    o.x = bu2f(a.x) + bu2f(b.x); o.y = bu2f(a.y) + bu2f(b.y);
    o.z = bu2f(a.z) + bu2f(b.z); o.w = bu2f(a.w) + bu2f(b.w);
    if (resid) {
        float4 r = *(const float4*)(resid + i * 4);
        o.x += r.x; o.y += r.y; o.z += r.z; o.w += r.w;
    }
    *(float4*)(outp + i * 4) = o;
}

// ---------------- transpose-cast: in[R][C] (ld, opt rowscale) -> bf16 out[C][R] ----------------
template<typename TI>
__global__ void k_tcast(const TI* __restrict__ in, long ldi, long sIn,
                        unsigned short* __restrict__ out, long ldo, long sOut,
                        const float* __restrict__ rowscale) {
    __shared__ float tile[64][65];
    const TI* ip = in + (long)blockIdx.z * sIn;
    unsigned short* op = out + (long)blockIdx.z * sOut;
    int r0 = blockIdx.y * 64, c0 = blockIdx.x * 64;
    int tid = threadIdx.x;
    int rr = tid >> 4, cc = (tid & 15) * 4;
    #pragma unroll
    for (int u = 0; u < 4; ++u) {
        int r = rr + u * 16;
        float sc = rowscale ? rowscale[r0 + r] : 1.0f;
        #pragma unroll
        for (int j = 0; j < 4; ++j)
            tile[r][cc + j] = ldval(ip + (long)(r0 + r) * ldi + c0 + cc + j) * sc;
    }
    __syncthreads();
    #pragma unroll
    for (int u = 0; u < 4; ++u) {
        int c = rr + u * 16;
        ushort4 o;
        o.x = f2bu(tile[cc + 0][c]); o.y = f2bu(tile[cc + 1][c]);
        o.z = f2bu(tile[cc + 2][c]); o.w = f2bu(tile[cc + 3][c]);
        *(ushort4*)(op + (long)(c0 + c) * ldo + r0 + cc) = o;
    }
}

// ---------------- fused transpose of o (rowscaled) and a from packed bf16 uv ----------------
__global__ void k_tcast2(const unsigned short* __restrict__ uv, const float* __restrict__ uscale,
                         unsigned short* __restrict__ t1, unsigned short* __restrict__ t2) {
    __shared__ float tile[64][65];
    int z = blockIdx.z;
    const unsigned short* ip = uv + (z ? 1024 : 0);
    unsigned short* op = z ? t2 : t1;
    int r0 = blockIdx.y * 64, c0 = blockIdx.x * 64;
    int tid = threadIdx.x;
    int rr = tid >> 4, cc = (tid & 15) * 4;
    #pragma unroll
    for (int u = 0; u < 4; ++u) {
        int r = rr + u * 16;
        float sc = z ? 1.0f : uscale[r0 + r];
        ushort4 v = *(const ushort4*)(ip + (long)(r0 + r) * 2048 + c0 + cc);
        tile[r][cc + 0] = bu2f(v.x) * sc; tile[r][cc + 1] = bu2f(v.y) * sc;
        tile[r][cc + 2] = bu2f(v.z) * sc; tile[r][cc + 3] = bu2f(v.w) * sc;
    }
    __syncthreads();
    #pragma unroll
    for (int u = 0; u < 4; ++u) {
        int c = rr + u * 16;
        ushort4 o;
        o.x = f2bu(tile[cc + 0][c]); o.y = f2bu(tile[cc + 1][c]);
        o.z = f2bu(tile[cc + 2][c]); o.w = f2bu(tile[cc + 3][c]);
        *(ushort4*)(op + (long)(c0 + c) * 4096 + r0 + cc) = o;
    }
}

// ---------------- bf16 MFMA GEMM, NT, 128x128 tile, BK=64 ----------------
template<int WRITE_BF16>
__global__ __launch_bounds__(256)
void k_bgemm(int K,
             const unsigned short* __restrict__ A, int lda, long sA,
             const unsigned short* __restrict__ B, int ldb, long sB,
             void* __restrict__ C, int ldc, long sCi, long sSplit, int nsplit,
             const float* __restrict__ scale_ptr, float fscale,
             const float* __restrict__ addp, int ldadd) {
    __shared__ unsigned short Asl[128 * 64];
    __shared__ unsigned short Bsl[128 * 64];
    int bz = blockIdx.z;
    int batch = bz, sp = 0;
    if (nsplit > 1) { batch = bz / nsplit; sp = bz - batch * nsplit; }
    int m0 = blockIdx.y * 128, n0 = blockIdx.x * 128;
    const unsigned short* Ap = A + (long)batch * sA + (long)sp * K;
    const unsigned short* Bp = B + (long)batch * sB + (long)sp * K;
    int tid = threadIdx.x, lane = tid & 63, wave = tid >> 6;
    int wr = wave >> 1, wc = wave & 1;
    f32x4 acc[4][4] = {};
    for (int k0 = 0; k0 < K; k0 += 64) {
        #pragma unroll
        for (int cc = 0; cc < 4; ++cc) {
            int bu = (wave * 4 + cc) * 64;
            int uidx = bu + lane;
            int r = uidx >> 3, slot = uidx & 7;
            int gu = slot ^ (r & 7);
            gload_lds16(Ap + (long)(m0 + r) * lda + k0 + gu * 8, Asl + bu * 8);
        }
        #pragma unroll
        for (int cc = 0; cc < 4; ++cc) {
            int bu = (wave * 4 + cc) * 64;
            int uidx = bu + lane;
            int r = uidx >> 3, slot = uidx & 7;
            int gu = slot ^ (r & 7);
            gload_lds16(Bp + (long)(n0 + r) * ldb + k0 + gu * 8, Bsl + bu * 8);
        }
        __syncthreads();
        #pragma unroll
        for (int ksub = 0; ksub < 2; ++ksub) {
            short8 av[4], bv[4];
            #pragma unroll
            for (int m = 0; m < 4; ++m) {
                int r = wr * 64 + m * 16 + (lane & 15);
                int slot = (ksub * 4 + (lane >> 4)) ^ (r & 7);
                av[m] = *(const short8*)(Asl + r * 64 + slot * 8);
            }
            #pragma unroll
            for (int n = 0; n < 4; ++n) {
                int r = wc * 64 + n * 16 + (lane & 15);
                int slot = (ksub * 4 + (lane >> 4)) ^ (r & 7);
                bv[n] = *(const short8*)(Bsl + r * 64 + slot * 8);
            }
            #pragma unroll
            for (int m = 0; m < 4; ++m)
                #pragma unroll
                for (int n = 0; n < 4; ++n)
                    acc[m][n] = __builtin_amdgcn_mfma_f32_16x16x32_bf16(av[m], bv[n], acc[m][n], 0, 0, 0);
        }
        __syncthreads();
    }
    float s = fscale * (scale_ptr ? scale_ptr[0] : 1.0f);
    long cbase = (long)batch * sCi + (long)sp * sSplit;
    int row0 = m0 + wr * 64, col0 = n0 + wc * 64 + (lane & 15);
    int rbase = (lane >> 4) * 4;
    #pragma unroll
    for (int m = 0; m < 4; ++m)
        #pragma unroll
        for (int i = 0; i < 4; ++i) {
            long row = row0 + m * 16 + rbase + i;
            #pragma unroll
            for (int n = 0; n < 4; ++n) {
                long col = col0 + n * 16;
                float v = acc[m][n][i] * s;
                if (addp) v += addp[row * (long)ldadd + col];
                long idx = cbase + row * ldc + col;
                if (WRITE_BF16) ((unsigned short*)C)[idx] = f2bu(v);
                else ((float*)C)[idx] = v;
            }
        }
}

// ---------------- flash-decoding split: KVBLK=64, DPP softmax (r9-best structure) ----------------
// item = (bh, strip32, K-chunk of <=8 tiles); 160 items/bh, 5120 items in 1280 blocks.
__global__ __launch_bounds__(256, 4)
void k_flash_split(const unsigned short* __restrict__ hq, const unsigned short* __restrict__ hk,
                   const unsigned short* __restrict__ hvT,
                   unsigned short* __restrict__ opart, float* __restrict__ mpart, float* __restrict__ lpart) {
    __shared__ unsigned short P_lds[4][32 * 72];
    int lane = threadIdx.x & 63, wave = threadIdx.x >> 6;
    unsigned short* P = P_lds[wave];
    int g = lane >> 4, c = lane & 15;
    unsigned bid = blockIdx.x;                           // 0..1279
    unsigned bswz = (bid & 7) * 160 + (bid >> 3);        // XCD-bijective: 160 blocks (=4 bh) per XCD
    unsigned gi = bswz * 4 + wave;                       // global item 0..5119
    unsigned bh = gi / 160, itr = gi % 160;
    int item = 159 - (int)itr;                           // longest chunks first
    int strip, chunk;
    if (item < 16)      { strip = item;                 chunk = 0; }
    else if (item < 48) { strip = 16 + (item - 16) / 2; chunk = (item - 16) & 1; }
    else if (item < 96) { strip = 32 + (item - 48) / 3; chunk = (item - 48) % 3; }
    else                { strip = 48 + (item - 96) / 4; chunk = (item - 96) & 3; }
    int q0 = strip * 32;
    int nt = (q0 + 32 + 63) >> 6;
    int ti0 = chunk * 8;
    int ti1 = ti0 + 8 < nt ? ti0 + 8 : nt;
    const unsigned short* qb = hq + (long)bh * Tc * 64;
    const unsigned short* kb = hk + (long)bh * Tc * 64;
    const unsigned short* vtb = hvT + (long)bh * 64 * Tc;

    short8 qf[2][2];
    #pragma unroll
    for (int mf = 0; mf < 2; ++mf)
        #pragma unroll
        for (int ks = 0; ks < 2; ++ks)
            qf[mf][ks] = *(const short8*)(qb + (long)(q0 + mf * 16 + c) * 64 + ks * 32 + g * 8);

    f32x4 o_acc[2][4] = {};
    float m_run[2][4], lpp[2][4];
    #pragma unroll
    for (int mf = 0; mf < 2; ++mf)
        #pragma unroll
        for (int i = 0; i < 4; ++i) { m_run[mf][i] = -3.0e38f; lpp[mf][i] = 0.f; }

    for (int ti = ti0; ti < ti1; ++ti) {
        int kt = ti * 64;
        // V loads issued early; latency overlaps K-wait + QK + softmax
        short8 vf[2][4];
        #pragma unroll
        for (int ks = 0; ks < 2; ++ks)
            #pragma unroll
            for (int df = 0; df < 4; ++df)
                vf[ks][df] = *(const short8*)(vtb + (long)(df * 16 + c) * Tc + kt + ks * 32 + g * 8);
        f32x4 s_acc[2][4] = {};
        #pragma unroll
        for (int ks = 0; ks < 2; ++ks) {
            short8 kf[4];
            #pragma unroll
            for (int nf = 0; nf < 4; ++nf)
                kf[nf] = *(const short8*)(kb + (long)(kt + nf * 16 + c) * 64 + ks * 32 + g * 8);
            #pragma unroll
            for (int mf = 0; mf < 2; ++mf)
                #pragma unroll
                for (int nf = 0; nf < 4; ++nf)
                    s_acc[mf][nf] = __builtin_amdgcn_mfma_f32_16x16x32_bf16(qf[mf][ks], kf[nf], s_acc[mf][nf], 0, 0, 0);
        }
        // causal mask: only the diagonal tile needs it
        if (ti == nt - 1) {
            #pragma unroll
            for (int mf = 0; mf < 2; ++mf)
                #pragma unroll
                for (int nf = 0; nf < 4; ++nf)
                    #pragma unroll
                    for (int i = 0; i < 4; ++i)
                        if ((kt + nf * 16 + c) > (q0 + mf * 16 + g * 4 + i)) s_acc[mf][nf][i] = -1.0e30f;
        }
        // raw-domain row max: in-lane over nf, then DPP tree over 16 lanes (VALU pipe)
        float pm[2][4];
        #pragma unroll
        for (int mf = 0; mf < 2; ++mf)
            #pragma unroll
            for (int i = 0; i < 4; ++i)
                pm[mf][i] = max16(fmaxf(fmaxf(s_acc[mf][0][i], s_acc[mf][1][i]),
                                        fmaxf(s_acc[mf][2][i], s_acc[mf][3][i])));
        // defer-max: rescale only if any row's scaled max grew beyond m_run + 8
        float mg = 0.f;
        #pragma unroll
        for (int mf = 0; mf < 2; ++mf)
            #pragma unroll
            for (int i = 0; i < 4; ++i) {
                pm[mf][i] *= 0.125f;
                mg = fmaxf(mg, pm[mf][i] - m_run[mf][i]);
            }
        if (__any(mg > 8.0f)) {
            #pragma unroll
            for (int mf = 0; mf < 2; ++mf)
                #pragma unroll
                for (int i = 0; i < 4; ++i) {
                    float mn = fmaxf(m_run[mf][i], pm[mf][i]);
                    float corr = __expf(m_run[mf][i] - mn);
                    m_run[mf][i] = mn;
                    lpp[mf][i] *= corr;
                    #pragma unroll
                    for (int df = 0; df < 4; ++df) o_acc[mf][df][i] *= corr;
                }
        }
        // exp (scale folded into fma) + P store + per-lane l accumulate
        #pragma unroll
        for (int mf = 0; mf < 2; ++mf)
            #pragma unroll
            for (int nf = 0; nf < 4; ++nf)
                #pragma unroll
                for (int i = 0; i < 4; ++i) {
                    float p = __expf(fmaf(s_acc[mf][nf][i], 0.125f, -m_run[mf][i]));
                    P[(mf * 16 + g * 4 + i) * 72 + nf * 16 + c] = f2bu(p);
                    lpp[mf][i] += p;
                }
        // PV
        #pragma unroll
        for (int ks = 0; ks < 2; ++ks) {
            short8 pa[2];
            #pragma unroll
            for (int mf = 0; mf < 2; ++mf)
                pa[mf] = *(const short8*)(P + (mf * 16 + c) * 72 + ks * 32 + g * 8);
            #pragma unroll
            for (int mf = 0; mf < 2; ++mf)
                #pragma unroll
                for (int df = 0; df < 4; ++df)
                    o_acc[mf][df] = __builtin_amdgcn_mfma_f32_16x16x32_bf16(pa[mf], vf[ks][df], o_acc[mf][df], 0, 0, 0);
        }
    }
    // one l-sum DPP tree for the whole chunk
    #pragma unroll
    for (int mf = 0; mf < 2; ++mf)
        #pragma unroll
        for (int i = 0; i < 4; ++i)
            lpp[mf][i] = sum16(lpp[mf][i]);
    long pbase = (long)(bh * 160 + item);
    #pragma unroll
    for (int mf = 0; mf < 2; ++mf)
        #pragma unroll
        for (int i = 0; i < 4; ++i) {
            int row_l = mf * 16 + g * 4 + i;
            #pragma unroll
            for (int df = 0; df < 4; ++df)
                opart[pbase * 2048 + row_l * 64 + df * 16 + c] = f2bu(o_acc[mf][df][i]);
            if (c == 0) {
                mpart[pbase * 32 + row_l] = m_run[mf][i];
                lpart[pbase * 32 + row_l] = lpp[mf][i];
            }
        }
}

// ---------------- flash merge: combine <=4 bf16 partials per (bh,strip) -> bf16 y ----------------
__global__ __launch_bounds__(256)
void k_flash_merge(const unsigned short* __restrict__ opart, const float* __restrict__ mpart,
                   const float* __restrict__ lpart, unsigned short* __restrict__ yout) {
    int bs = blockIdx.x;
    int bh = bs >> 6, strip = bs & 63;
    int b = bh >> 4, h = bh & 15;
    int np, base;
    if (strip < 16)      { np = 1; base = strip; }
    else if (strip < 32) { np = 2; base = 16 + (strip - 16) * 2; }
    else if (strip < 48) { np = 3; base = 48 + (strip - 32) * 3; }
    else                 { np = 4; base = 96 + (strip - 48) * 4; }
    long p0 = (long)(bh * 160 + base);
    int tid = threadIdx.x;
    int r = tid >> 3, c0 = (tid & 7) * 8;
    float M = -3.0e38f;
    for (int p = 0; p < np; ++p) M = fmaxf(M, mpart[(p0 + p) * 32 + r]);
    float L = 0.f;
    float acc[8] = {};
    for (int p = 0; p < np; ++p) {
        float sc = __expf(mpart[(p0 + p) * 32 + r] - M);
        L += lpart[(p0 + p) * 32 + r] * sc;
        const unsigned short* op = opart + (p0 + p) * 2048 + r * 64 + c0;
        ushort4 a = *(const ushort4*)op;
        ushort4 bq = *(const ushort4*)(op + 4);
        acc[0] += bu2f(a.x) * sc; acc[1] += bu2f(a.y) * sc;
        acc[2] += bu2f(a.z) * sc; acc[3] += bu2f(a.w) * sc;
        acc[4] += bu2f(bq.x) * sc; acc[5] += bu2f(bq.y) * sc;
        acc[6] += bu2f(bq.z) * sc; acc[7] += bu2f(bq.w) * sc;
    }
    float inv = 1.0f / L;
    long row = (long)b * Tc + strip * 32 + r;
    unsigned short* yp = yout + row * 1024 + h * 64 + c0;
    ushort4 o1, o2;
    o1.x = f2bu(acc[0] * inv); o1.y = f2bu(acc[1] * inv); o1.z = f2bu(acc[2] * inv); o1.w = f2bu(acc[3] * inv);
    o2.x = f2bu(acc[4] * inv); o2.y = f2bu(acc[5] * inv); o2.z = f2bu(acc[6] * inv); o2.w = f2bu(acc[7] * inv);
    *(ushort4*)yp = o1;
    *(ushort4*)(yp + 4) = o2;
}

// ---------------- AFT gated cumsum (bf16 qkv): 3-pass chunked ----------------
__global__ void k_aft_p1(const unsigned short* __restrict__ qkv, float* __restrict__ cw, float* __restrict__ cs) {
    int id = blockIdx.x * TPB + threadIdx.x;
    int bc = id & 2047, ch = id >> 11;
    int b = bc >> 10, c = bc & 1023;
    const unsigned short* base = qkv + ((long)(b * Tc + ch * CHL)) * 3072 + c;
    float sw = 0.f, sv = 0.f;
    for (int i = 0; i < CHL; ++i) {
        float k = bu2f(base[1024]), v = bu2f(base[2048]);
        float e = __expf(k);
        sw += e; sv += e * v;
        base += 3072;
    }
    cw[ch * 2048 + bc] = sw; cs[ch * 2048 + bc] = sv;
}

__global__ void k_aft_p2(float* __restrict__ cw, float* __restrict__ cs) {
    int bc = blockIdx.x * TPB + threadIdx.x;
    float rw = 0.f, rv = 0.f;
    for (int ch = 0; ch < NCH; ++ch) {
        long idx = (long)ch * 2048 + bc;
        float tw = cw[idx], tv = cs[idx];
        cw[idx] = rw; cs[idx] = rv; rw += tw; rv += tv;
    }
}

__global__ void k_aft_p3(const unsigned short* __restrict__ qkv, const float* __restrict__ cw,
                         const float* __restrict__ cs, unsigned short* __restrict__ y) {
    int id = blockIdx.x * TPB + threadIdx.x;
    int bc = id & 2047, ch = id >> 11;
    int b = bc >> 10, c = bc & 1023;
    float aw = cw[ch * 2048 + bc], av = cs[ch * 2048 + bc];
    long t0 = (long)b * Tc + ch * CHL;
    const unsigned short* base = qkv + t0 * 3072 + c;
    unsigned short* yp = y + t0 * 1024 + c;
    for (int i = 0; i < CHL; ++i) {
        float q = bu2f(base[0]), k = bu2f(base[1024]), v = bu2f(base[2048]);
        float e = __expf(k);
        av += e * v; aw += e;
        float sig = 1.0f / (1.0f + __expf(-q));
        yp[0] = f2bu(sig * av / (aw + 1e-6f));
        base += 3072; yp += 1024;
    }
}

// ---------------- fused u*silu(v) -> bf16 + rowrms(u), bf16 uv in (block per row) ----------------
__global__ void k_silu_rms(const unsigned short* __restrict__ uv, unsigned short* __restrict__ g,
                           float* __restrict__ rs) {
    __shared__ float red[TPB];
    long row = blockIdx.x;
    const unsigned short* up = uv + row * 2048;
    ushort4 u4 = *(const ushort4*)(up + threadIdx.x * 4);
    ushort4 v4 = *(const ushort4*)(up + 1024 + threadIdx.x * 4);
    float u0 = bu2f(u4.x), u1 = bu2f(u4.y), u2 = bu2f(u4.z), u3 = bu2f(u4.w);
    float v0 = bu2f(v4.x), v1 = bu2f(v4.y), v2 = bu2f(v4.z), v3 = bu2f(v4.w);
    ushort4 o;
    o.x = f2bu(u0 * v0 / (1.f + __expf(-v0)));
    o.y = f2bu(u1 * v1 / (1.f + __expf(-v1)));
    o.z = f2bu(u2 * v2 / (1.f + __expf(-v2)));
    o.w = f2bu(u3 * v3 / (1.f + __expf(-v3)));
    *(ushort4*)(g + row * 1024 + threadIdx.x * 4) = o;
    red[threadIdx.x] = u0 * u0 + u1 * u1 + u2 * u2 + u3 * u3;
    __syncthreads();
    for (int off = 128; off > 0; off >>= 1) {
        if (threadIdx.x < off) red[threadIdx.x] += red[threadIdx.x + off];
        __syncthreads();
    }
    if (threadIdx.x == 0) rs[row] = rsqrtf(red[0] / 1024.0f + F32_EPS);
}

// ---------------- u * silu(v) -> bf16 (final swiglu, bf16 in) ----------------
__global__ void k_silu_gate(const unsigned short* __restrict__ uv, unsigned short* __restrict__ g, long n4) {
    long i = (long)blockIdx.x * TPB + threadIdx.x;
    if (i >= n4) return;
    long r = i >> 8, c4 = i & 255;
    ushort4 u4 = *(const ushort4*)(uv + r * 2048 + c4 * 4);
    ushort4 v4 = *(const ushort4*)(uv + r * 2048 + 1024 + c4 * 4);
    float u0 = bu2f(u4.x), u1 = bu2f(u4.y), u2 = bu2f(u4.z), u3 = bu2f(u4.w);
    float v0 = bu2f(v4.x), v1 = bu2f(v4.y), v2 = bu2f(v4.z), v3 = bu2f(v4.w);
    ushort4 o;
    o.x = f2bu(u0 * v0 / (1.f + __expf(-v0)));
    o.y = f2bu(u1 * v1 / (1.f + __expf(-v1)));
    o.z = f2bu(u2 * v2 / (1.f + __expf(-v2)));
    o.w = f2bu(u3 * v3 / (1.f + __expf(-v3)));
    *(ushort4*)(g + r * 1024 + c4 * 4) = o;
}

// ---------------- w_out = p*s*silu(w_in) + w_in  (also emits bf16 copy) ----------------
__global__ void k_wupdate(float* __restrict__ wout, const float* __restrict__ win,
                          const float* __restrict__ p, const float* __restrict__ scale,
                          unsigned short* __restrict__ wb, long n4) {
    long i = (long)blockIdx.x * TPB + threadIdx.x;
    if (i >= n4) return;
    float s = scale[0];
    float4 wv = *(const float4*)(win + i * 4);
    float4 pv = *(const float4*)(p + i * 4);
    float4 o;
    o.x = pv.x * s * (wv.x / (1.f + __expf(-wv.x))) + wv.x;
    o.y = pv.y * s * (wv.y / (1.f + __expf(-wv.y))) + wv.y;
    o.z = pv.z * s * (wv.z / (1.f + __expf(-wv.z))) + wv.z;
    o.w = pv.w * s * (wv.w / (1.f + __expf(-wv.w))) + wv.w;
    *(float4*)(wout + i * 4) = o;
    ushort4 ob; ob.x = f2bu(o.x); ob.y = f2bu(o.y); ob.z = f2bu(o.z); ob.w = f2bu(o.w);
    *(ushort4*)(wb + i * 4) = ob;
}

// ---------------- 4-slab reduce + scale + row softmax -> fp32 out ----------------
__global__ void k_softmax4(const float* __restrict__ parts, float* __restrict__ outb, float fscale) {
    __shared__ float red[TPB];
    __shared__ float rowbuf[1024];
    long row = blockIdx.x;
    const float* p0 = parts + row * 1024;
    for (int c = threadIdx.x; c < 1024; c += TPB) {
        float v = p0[c] + p0[c + 1048576] + p0[c + 2097152] + p0[c + 3145728];
        rowbuf[c] = v * fscale;
    }
    __syncthreads();
    float m = -3.0e38f;
    for (int c = threadIdx.x; c < 1024; c += TPB) m = fmaxf(m, rowbuf[c]);
    red[threadIdx.x] = m; __syncthreads();
    for (int o = 128; o > 0; o >>= 1) {
        if (threadIdx.x < o) red[threadIdx.x] = fmaxf(red[threadIdx.x], red[threadIdx.x + o]);
        __syncthreads();
    }
    m = red[0]; __syncthreads();
    float sum = 0.f;
    for (int c = threadIdx.x; c < 1024; c += TPB) sum += __expf(rowbuf[c] - m);
    red[threadIdx.x] = sum; __syncthreads();
    for (int o = 128; o > 0; o >>= 1) {
        if (threadIdx.x < o) red[threadIdx.x] += red[threadIdx.x + o];
        __syncthreads();
    }
    float inv = 1.0f / red[0];
    for (int c = threadIdx.x; c < 1024; c += TPB)
        outb[row * 1024 + c] = __expf(rowbuf[c] - m) * inv;
}

// ---------------- tea: rotary + per-head rmsnorm + split, bf16 in/out ----------------
__global__ void k_rot_split(const unsigned short* __restrict__ qkvp, const float* __restrict__ cosp,
                            const float* __restrict__ sinp, unsigned short* __restrict__ hq,
                            unsigned short* __restrict__ hk, unsigned short* __restrict__ hv) {
    __shared__ float row[3072];
    __shared__ float cs[32], sn[32];
    int bt = blockIdx.x;
    int b = bt >> 11, t = bt & 2047;
    const unsigned short* src = qkvp + (long)bt * 3072;
    #pragma unroll
    for (int u = 0; u < 3; ++u) {
        int idx = threadIdx.x + u * 256;
        ushort4 v = *(const ushort4*)(src + idx * 4);
        row[idx * 4 + 0] = bu2f(v.x); row[idx * 4 + 1] = bu2f(v.y);
        row[idx * 4 + 2] = bu2f(v.z); row[idx * 4 + 3] = bu2f(v.w);
    }
    if (threadIdx.x < 32) { cs[threadIdx.x] = cosp[t * 32 + threadIdx.x]; sn[threadIdx.x] = sinp[t * 32 + threadIdx.x]; }
    __syncthreads();
    int h = threadIdx.x >> 4, li = threadIdx.x & 15;
    int base = h * 192;
    long obase = ((long)(b * Hc + h) * Tc + t) * 64 + li * 4;
    {
        float r[4]; float ss = 0.f;
        #pragma unroll
        for (int j = 0; j < 4; ++j) {
            int d = li * 4 + j;
            float val = (d < 32) ? (row[base + d] * cs[d] + row[base + d + 32] * sn[d])
                                 : (-row[base + d - 32] * sn[d - 32] + row[base + d] * cs[d - 32]);
            r[j] = val; ss += val * val;
        }
        ss = sum16(ss);
        float sc = rsqrtf(ss / 64.0f + F32_EPS);
        ushort4 o; o.x = f2bu(r[0] * sc); o.y = f2bu(r[1] * sc); o.z = f2bu(r[2] * sc); o.w = f2bu(r[3] * sc);
        *(ushort4*)(hq + obase) = o;
    }
    {
        int kb = base + 64;
        float r[4]; float ss = 0.f;
        #pragma unroll
        for (int j = 0; j < 4; ++j) {
            int d = li * 4 + j;
            float val = (d < 32) ? (row[kb + d] * cs[d] + row[kb + d + 32] * sn[d])
                                 : (-row[kb + d - 32] * sn[d - 32] + row[kb + d] * cs[d - 32]);
            r[j] = val; ss += val * val;
        }
        ss = sum16(ss);
        float sc = rsqrtf(ss / 64.0f + F32_EPS);
        ushort4 o; o.x = f2bu(r[0] * sc); o.y = f2bu(r[1] * sc); o.z = f2bu(r[2] * sc); o.w = f2bu(r[3] * sc);
        *(ushort4*)(hk + obase) = o;
    }
    {
        ushort4 o;
        o.x = f2bu(row[base + 128 + li * 4 + 0]); o.y = f2bu(row[base + 128 + li * 4 + 1]);
        o.z = f2bu(row[base + 128 + li * 4 + 2]); o.w = f2bu(row[base + 128 + li * 4 + 3]);
        *(ushort4*)(hv + obase) = o;
    }
}

extern "C" void kernel_launch(void* const* d_in, const int* in_sizes, int n_in,
                              void* d_out, int out_size, void* d_ws, size_t ws_size,
                              hipStream_t stream) {
    const float* x_in = (const float*)d_in[0];
    const float* w_in = (const float*)d_in[1];
    const float* cos_in = (const float*)d_in[2];
    const float* sin_in = (const float*)d_in[3];
    float* out = (float*)d_out;
    float* ws = (float*)d_ws;

    long off = 0;
    float* w_cur = ws + off;  off += (long)WR * Ec;
    float* w_tmp = ws + off;  off += (long)WR * Ec;   // also: oa split-K partials (4M floats)
    float* xbuf  = ws + off;  off += BT * Ec;
    float* R     = ws + off;  off += BT * 3L * QKVc;  // bf16 qkvb+uvb | bf16 opart | split-K slabs
    float* oab   = ws + off;  off += (long)Ec * Ec;   // also: flash m/l partials
    float* red   = ws + off;  off += 2048;
    float* scales= ws + off;  off += 16;
    float* uscale= ws + off;  off += 4096;
    float* chw   = ws + off;  off += 2048L * NCH;
    float* chs   = ws + off;  off += 2048L * NCH;
    unsigned short* qkvb  = (unsigned short*)R;          // 12.58M ushorts
    unsigned short* uvb   = qkvb + 12582912L;            // 8.39M ushorts
    unsigned short* opartb= qkvb;                         // final-phase alias
    unsigned short* wsplit = qkvb;                        // w@oa split slabs (2 x 6.29M) - qkv dead
    unsigned short* osplit = uvb;                         // out-proj split slabs (2 x 4.19M) - uv dead
    float* mpart = oab;
    float* lpart = oab + 5120L * 32;

    unsigned short* bp = (unsigned short*)(ws + off);
    long bo = 0;
    unsigned short* wb  = bp + bo; bo += (long)WR * Ec;
    unsigned short* xbn = bp + bo; bo += BT * Ec;
    unsigned short* ybn = bp + bo; bo += BT * Ec;
    unsigned short* gbn = bp + bo; bo += BT * Ec;
    unsigned short* t1  = bp + bo; bo += BT * Ec;            // o^T | hq
    unsigned short* t2  = bp + bo; bo += BT * Ec;            // v^T | hk
    unsigned short* t3  = bp + bo; bo += BT * Ec;            // oa^T | hvS
    unsigned short* t4  = bp + bo; bo += BT * Ec;            // hvT

    const float rsWR = 1.0f / sqrtf(6144.0f);
    const long wsw = 3072L * 1024, wout = 5120L * 1024;

    // one-time bf16 copy of w (from input)
    k_cast_bf16<<<(int)(((long)WR * Ec / 4) / TPB), TPB, 0, stream>>>(w_in, wb, (long)WR * Ec / 4);

    for (int layer = 0; layer < 2; ++layer) {
        const float* wsrc = layer == 0 ? w_in : w_cur;   // fp32 weights
        const float* xsrc = layer == 0 ? x_in : xbuf;    // fp32 activations
        k_std_partial3<<<dim3(256, 3), TPB, 0, stream>>>(wsrc, red);
        k_std_final3<<<1, TPB, 0, stream>>>(red, scales);
        k_rms1024b<<<BT, TPB, 0, stream>>>(xsrc, xbn, 1024, 1024);
        k_bgemm<1><<<dim3(24, 32, 1), TPB, 0, stream>>>(
            1024, xbn, 1024, 0, wb, 1024, 0, qkvb, 3072, 0, 0, 1, scales + 0, 1.0f, nullptr, 0);
        k_rms_qk<<<8192, TPB, 0, stream>>>(qkvb);
        k_aft_p1<<<(2048 * NCH) / TPB, TPB, 0, stream>>>(qkvb, chw, chs);
        k_aft_p2<<<2048 / TPB, TPB, 0, stream>>>(chw, chs);
        k_aft_p3<<<(2048 * NCH) / TPB, TPB, 0, stream>>>(qkvb, chw, chs, ybn);
        k_bgemm<1><<<dim3(16, 32, 1), TPB, 0, stream>>>(
            1024, ybn, 1024, 0, wb + wsw, 1024, 0, uvb, 2048, 0, 0, 1, scales + 1, 1.0f, nullptr, 0);
        k_silu_rms<<<BT, TPB, 0, stream>>>(uvb, gbn, uscale);
        k_tcast2<<<dim3(16, 64, 2), TPB, 0, stream>>>(uvb, uscale, t1, t2);
        // oa = softmax(o^T @ a * E^-0.5), split-K x4 into w_tmp partials
        k_bgemm<0><<<dim3(8, 8, 4), TPB, 0, stream>>>(
            1024, t1, 4096, 0, t2, 4096, 0, w_tmp, 1024, 0, 1048576L, 4, nullptr, 1.0f, nullptr, 0);
        k_softmax4<<<1024, TPB, 0, stream>>>(w_tmp, oab, 0.03125f);
        k_tcast<float><<<dim3(16, 16, 1), TPB, 0, stream>>>(oab, 1024, 0, t3, 1024, 0, nullptr);
        // x' = x + g @ w_out^T * s2 : split-K x2 (bf16 partials in dead uv region) + merge
        k_bgemm<1><<<dim3(8, 32, 2), TPB, 0, stream>>>(
            512, gbn, 1024, 0, wb + wout, 1024, 0, osplit, 1024, 0, 4194304L, 2, scales + 2, 1.0f, nullptr, 0);
        k_merge2<<<(int)((BT * 1024 / 4) / TPB), TPB, 0, stream>>>(
            osplit, osplit + 4194304L, xsrc, xbuf, BT * 1024 / 4);
        // w_tmp = w @ oa : split-K x2 (bf16 partials in dead qkv region) + merge
        k_bgemm<1><<<dim3(8, 48, 2), TPB, 0, stream>>>(
            512, wb, 1024, 0, t3, 1024, 0, wsplit, 1024, 0, 6291456L, 2, nullptr, 1.0f, nullptr, 0);
        k_merge2<<<(int)(((long)WR * 1024 / 4) / TPB), TPB, 0, stream>>>(
            wsplit, wsplit + 6291456L, nullptr, w_tmp, (long)WR * 1024 / 4);
        k_std_partial<<<256, TPB, 0, stream>>>(w_tmp, (long)WR * 1024, red);
        k_std_final<<<1, TPB, 0, stream>>>(red, (float)((long)WR * 1024), rsWR, scales + 3);
        k_wupdate<<<(int)(((long)WR * 1024 / 4) / TPB), TPB, 0, stream>>>(
            w_cur, wsrc, w_tmp, scales + 3, wb, (long)WR * 1024 / 4);
    }

    // -------- final tea (no w_norm) --------
    k_rms1024b<<<BT, TPB, 0, stream>>>(xbuf, xbn, 1024, 1024);
    k_bgemm<1><<<dim3(24, 32, 1), TPB, 0, stream>>>(
        1024, xbn, 1024, 0, wb, 1024, 0, qkvb, 3072, 0, 0, 1, nullptr, 1.0f, nullptr, 0);
    k_rot_split<<<BT, TPB, 0, stream>>>(qkvb, cos_in, sin_in, t1, t2, t3);
    k_tcast<unsigned short><<<dim3(1, 32, 32), TPB, 0, stream>>>(
        t3, 64, (long)Tc * 64, t4, 2048, (long)Tc * 64, nullptr);
    // flash-decoding: 5120 items in 1280 blocks (4 waves/block, independent), then merge
    k_flash_split<<<dim3(1280), TPB, 0, stream>>>(t1, t2, t4, opartb, mpart, lpart);
    k_flash_merge<<<dim3(2048), TPB, 0, stream>>>(opartb, mpart, lpart, ybn);
    // final swiglu -> d_out
    k_bgemm<1><<<dim3(16, 32, 1), TPB, 0, stream>>>(
        1024, ybn, 1024, 0, wb + wsw, 1024, 0, uvb, 2048, 0, 0, 1, nullptr, 1.0f, nullptr, 0);
    k_silu_gate<<<(int)((BT * 1024 / 4) / TPB), TPB, 0, stream>>>(uvb, gbn, BT * 1024 / 4);
    // final out-proj: split-K x2 into dead qkvb region + merge(+x residual) -> out
    k_bgemm<1><<<dim3(8, 32, 2), TPB, 0, stream>>>(
        512, gbn, 1024, 0, wb + wout, 1024, 0, qkvb, 1024, 0, 4194304L, 2, nullptr, 1.0f, nullptr, 0);
    k_merge2<<<(int)((BT * 1024 / 4) / TPB), TPB, 0, stream>>>(
        qkvb, qkvb + 4194304L, xbuf, out, BT * 1024 / 4);
}

// Round 13
// 775.836 us; speedup vs baseline: 1.1149x; 1.1149x over previous
//
#include <hip/hip_runtime.h>
#include <hip/hip_bf16.h>
#include <math.h>

#define TPB 256

constexpr int Bc = 2, Tc = 2048, Ec = 1024, QKVc = 1024, Hc = 16, DHc = 64;
constexpr long BT = (long)Bc * Tc;     // 4096
constexpr int WR = 5 * QKVc + Ec;      // 6144
constexpr float F32_EPS = 1.1920928955078125e-07f;
constexpr int NCH = 64, CHL = Tc / NCH;

typedef __attribute__((ext_vector_type(8))) short short8;
typedef __attribute__((ext_vector_type(4))) float f32x4;

__device__ __forceinline__ unsigned short f2bu(float f) {
    union { __hip_bfloat16 h; unsigned short u; } c; c.h = __float2bfloat16(f); return c.u;
}
__device__ __forceinline__ float bu2f(unsigned short u) {
    union { __hip_bfloat16 h; unsigned short u; } c; c.u = u; return __bfloat162float(c.h);
}
__device__ __forceinline__ float ldval(const float* p) { return *p; }
__device__ __forceinline__ float ldval(const unsigned short* p) { return bu2f(*p); }

__device__ __forceinline__ void gload_lds16(const void* g, void* l) {
    __builtin_amdgcn_global_load_lds((const __attribute__((address_space(1))) void*)g,
                                     (__attribute__((address_space(3))) void*)l, 16, 0, 0);
}

// ---- DPP cross-lane (VALU pipe): reduce over 16-lane groups ----
template<int CTRL>
__device__ __forceinline__ float dppf(float x) {
    union { float f; int i; } a, b;
    a.f = x;
    b.i = __builtin_amdgcn_update_dpp(0, a.i, CTRL, 0xF, 0xF, true);
    return b.f;
}
__device__ __forceinline__ float max16(float v) {
    v = fmaxf(v, dppf<0xB1>(v));    // quad_perm xor1
    v = fmaxf(v, dppf<0x4E>(v));    // quad_perm xor2
    v = fmaxf(v, dppf<0x124>(v));   // row_ror:4
    v = fmaxf(v, dppf<0x128>(v));   // row_ror:8
    return v;
}
__device__ __forceinline__ float sum16(float v) {
    v += dppf<0xB1>(v);
    v += dppf<0x4E>(v);
    v += dppf<0x124>(v);
    v += dppf<0x128>(v);
    return v;
}

// ---------------- fused 3-segment global std (ddof=1) for w_qkv/w_sw/w_out ----------------
__global__ void k_std_partial3(const float* __restrict__ w, float* __restrict__ out) {
    __shared__ float ls[TPB], lss[TPB];
    int seg = blockIdx.y;
    long base = (seg == 0) ? 0L : (seg == 1 ? 3072L * 1024 : 5120L * 1024);
    long n    = (seg == 0) ? 3072L * 1024 : (seg == 1 ? 2048L * 1024 : 1024L * 1024);
    const float* p = w + base;
    float s = 0.f, ss = 0.f;
    for (long i = (long)blockIdx.x * TPB + threadIdx.x; i < n; i += 256L * TPB) {
        float v = p[i]; s += v; ss += v * v;
    }
    ls[threadIdx.x] = s; lss[threadIdx.x] = ss; __syncthreads();
    for (int o = 128; o > 0; o >>= 1) {
        if (threadIdx.x < o) { ls[threadIdx.x] += ls[threadIdx.x + o]; lss[threadIdx.x] += lss[threadIdx.x + o]; }
        __syncthreads();
    }
    if (threadIdx.x == 0) { out[seg * 512 + blockIdx.x] = ls[0]; out[seg * 512 + 256 + blockIdx.x] = lss[0]; }
}

__global__ void k_std_final3(const float* __restrict__ part, float* __restrict__ scales) {
    __shared__ float ls[TPB], lss[TPB];
    for (int seg = 0; seg < 3; ++seg) {
        ls[threadIdx.x] = part[seg * 512 + threadIdx.x];
        lss[threadIdx.x] = part[seg * 512 + 256 + threadIdx.x];
        __syncthreads();
        for (int o = 128; o > 0; o >>= 1) {
            if (threadIdx.x < o) { ls[threadIdx.x] += ls[threadIdx.x + o]; lss[threadIdx.x] += lss[threadIdx.x + o]; }
            __syncthreads();
        }
        if (threadIdx.x == 0) {
            float n = (seg == 0) ? 3145728.0f : (seg == 1 ? 2097152.0f : 1048576.0f);
            float var = (lss[0] - ls[0] * ls[0] / n) / (n - 1.0f);
            scales[seg] = 0.03125f / (sqrtf(fmaxf(var, 0.0f)) + 1e-8f);
        }
        __syncthreads();
    }
}

// ---------------- generic global std (for w_tmp) ----------------
__global__ void k_std_partial(const float* __restrict__ p, long n, float* __restrict__ out) {
    __shared__ float ls[TPB], lss[TPB];
    float s = 0.f, ss = 0.f;
    for (long i = (long)blockIdx.x * TPB + threadIdx.x; i < n; i += (long)gridDim.x * TPB) {
        float v = p[i]; s += v; ss += v * v;
    }
    ls[threadIdx.x] = s; lss[threadIdx.x] = ss; __syncthreads();
    for (int o = 128; o > 0; o >>= 1) {
        if (threadIdx.x < o) { ls[threadIdx.x] += ls[threadIdx.x + o]; lss[threadIdx.x] += lss[threadIdx.x + o]; }
        __syncthreads();
    }
    if (threadIdx.x == 0) { out[blockIdx.x] = ls[0]; out[gridDim.x + blockIdx.x] = lss[0]; }
}

__global__ void k_std_final(const float* __restrict__ part, float n, float rs, float* __restrict__ scale) {
    __shared__ float ls[TPB], lss[TPB];
    ls[threadIdx.x] = part[threadIdx.x];
    lss[threadIdx.x] = part[TPB + threadIdx.x];
    __syncthreads();
    for (int o = 128; o > 0; o >>= 1) {
        if (threadIdx.x < o) { ls[threadIdx.x] += ls[threadIdx.x + o]; lss[threadIdx.x] += lss[threadIdx.x + o]; }
        __syncthreads();
    }
    if (threadIdx.x == 0) {
        float var = (lss[0] - ls[0] * ls[0] / n) / (n - 1.0f);
        scale[0] = rs / (sqrtf(fmaxf(var, 0.0f)) + 1e-8f);
    }
}

// ---------------- in-place rmsnorm of q and k halves of bf16 qkv (grid 8192) ----------------
__global__ void k_rms_qk(unsigned short* __restrict__ qkv) {
    __shared__ float red[TPB];
    int bid = blockIdx.x;
    long row = bid >> 1; int half = bid & 1;
    unsigned short* p = qkv + row * 3072 + half * 1024;
    ushort4 v = *(const ushort4*)(p + threadIdx.x * 4);
    float f0 = bu2f(v.x), f1 = bu2f(v.y), f2 = bu2f(v.z), f3 = bu2f(v.w);
    red[threadIdx.x] = f0 * f0 + f1 * f1 + f2 * f2 + f3 * f3;
    __syncthreads();
    for (int o = 128; o > 0; o >>= 1) {
        if (threadIdx.x < o) red[threadIdx.x] += red[threadIdx.x + o];
        __syncthreads();
    }
    float sc = rsqrtf(red[0] / 1024.0f + F32_EPS);
    ushort4 o4; o4.x = f2bu(f0 * sc); o4.y = f2bu(f1 * sc); o4.z = f2bu(f2 * sc); o4.w = f2bu(f3 * sc);
    *(ushort4*)(p + threadIdx.x * 4) = o4;
}

// ---------------- rmsnorm over 1024 cols, fp32 in -> bf16 out ----------------
__global__ void k_rms1024b(const float* __restrict__ in, unsigned short* __restrict__ out, long ldin, long ldout) {
    __shared__ float red[TPB];
    long row = blockIdx.x;
    float4 v = *(const float4*)(in + row * ldin + threadIdx.x * 4);
    float ss = v.x * v.x + v.y * v.y + v.z * v.z + v.w * v.w;
    red[threadIdx.x] = ss; __syncthreads();
    for (int o = 128; o > 0; o >>= 1) {
        if (threadIdx.x < o) red[threadIdx.x] += red[threadIdx.x + o];
        __syncthreads();
    }
    float sc = rsqrtf(red[0] / 1024.0f + F32_EPS);
    ushort4 o4; o4.x = f2bu(v.x * sc); o4.y = f2bu(v.y * sc); o4.z = f2bu(v.z * sc); o4.w = f2bu(v.w * sc);
    *(ushort4*)(out + row * ldout + threadIdx.x * 4) = o4;
}

// ---------------- fp32 -> bf16 cast ----------------
__global__ void k_cast_bf16(const float* __restrict__ in, unsigned short* __restrict__ out, long n4) {
    long i = (long)blockIdx.x * TPB + threadIdx.x;
    if (i >= n4) return;
    float4 v = *(const float4*)(in + i * 4);
    ushort4 o; o.x = f2bu(v.x); o.y = f2bu(v.y); o.z = f2bu(v.z); o.w = f2bu(v.w);
    *(ushort4*)(out + i * 4) = o;
}

// ---------------- merge 2 bf16 split-K slabs -> fp32 (+opt residual) ----------------
__global__ void k_merge2(const unsigned short* __restrict__ p0, const unsigned short* __restrict__ p1,
                         const float* __restrict__ resid, float* __restrict__ outp, long n4) {
    long i = (long)blockIdx.x * TPB + threadIdx.x;
    if (i >= n4) return;
    ushort4 a = *(const ushort4*)(p0 + i * 4);
    ushort4 b = *(const ushort4*)(p1 + i * 4);
    float4 o;
    o.x = bu2f(a.x) + bu2f(b.x); o.y = bu2f(a.y) + bu2f(b.y);
    o.z = bu2f(a.z) + bu2f(b.z); o.w = bu2f(a.w) + bu2f(b.w);
    if (resid) {
        float4 r = *(const float4*)(resid + i * 4);
        o.x += r.x; o.y += r.y; o.z += r.z; o.w += r.w;
    }
    *(float4*)(outp + i * 4) = o;
}

// ---------------- transpose-cast: in[R][C] (ld, opt rowscale) -> bf16 out[C][R] ----------------
template<typename TI>
__global__ void k_tcast(const TI* __restrict__ in, long ldi, long sIn,
                        unsigned short* __restrict__ out, long ldo, long sOut,
                        const float* __restrict__ rowscale) {
    __shared__ float tile[64][65];
    const TI* ip = in + (long)blockIdx.z * sIn;
    unsigned short* op = out + (long)blockIdx.z * sOut;
    int r0 = blockIdx.y * 64, c0 = blockIdx.x * 64;
    int tid = threadIdx.x;
    int rr = tid >> 4, cc = (tid & 15) * 4;
    #pragma unroll
    for (int u = 0; u < 4; ++u) {
        int r = rr + u * 16;
        float sc = rowscale ? rowscale[r0 + r] : 1.0f;
        #pragma unroll
        for (int j = 0; j < 4; ++j)
            tile[r][cc + j] = ldval(ip + (long)(r0 + r) * ldi + c0 + cc + j) * sc;
    }
    __syncthreads();
    #pragma unroll
    for (int u = 0; u < 4; ++u) {
        int c = rr + u * 16;
        ushort4 o;
        o.x = f2bu(tile[cc + 0][c]); o.y = f2bu(tile[cc + 1][c]);
        o.z = f2bu(tile[cc + 2][c]); o.w = f2bu(tile[cc + 3][c]);
        *(ushort4*)(op + (long)(c0 + c) * ldo + r0 + cc) = o;
    }
}

// ---------------- fused transpose of o (rowscaled) and a from packed bf16 uv ----------------
__global__ void k_tcast2(const unsigned short* __restrict__ uv, const float* __restrict__ uscale,
                         unsigned short* __restrict__ t1, unsigned short* __restrict__ t2) {
    __shared__ float tile[64][65];
    int z = blockIdx.z;
    const unsigned short* ip = uv + (z ? 1024 : 0);
    unsigned short* op = z ? t2 : t1;
    int r0 = blockIdx.y * 64, c0 = blockIdx.x * 64;
    int tid = threadIdx.x;
    int rr = tid >> 4, cc = (tid & 15) * 4;
    #pragma unroll
    for (int u = 0; u < 4; ++u) {
        int r = rr + u * 16;
        float sc = z ? 1.0f : uscale[r0 + r];
        ushort4 v = *(const ushort4*)(ip + (long)(r0 + r) * 2048 + c0 + cc);
        tile[r][cc + 0] = bu2f(v.x) * sc; tile[r][cc + 1] = bu2f(v.y) * sc;
        tile[r][cc + 2] = bu2f(v.z) * sc; tile[r][cc + 3] = bu2f(v.w) * sc;
    }
    __syncthreads();
    #pragma unroll
    for (int u = 0; u < 4; ++u) {
        int c = rr + u * 16;
        ushort4 o;
        o.x = f2bu(tile[cc + 0][c]); o.y = f2bu(tile[cc + 1][c]);
        o.z = f2bu(tile[cc + 2][c]); o.w = f2bu(tile[cc + 3][c]);
        *(ushort4*)(op + (long)(c0 + c) * 4096 + r0 + cc) = o;
    }
}

// ---------------- bf16 MFMA GEMM, NT, 128x128 tile, BK=64 ----------------
template<int WRITE_BF16>
__global__ __launch_bounds__(256)
void k_bgemm(int K,
             const unsigned short* __restrict__ A, int lda, long sA,
             const unsigned short* __restrict__ B, int ldb, long sB,
             void* __restrict__ C, int ldc, long sCi, long sSplit, int nsplit,
             const float* __restrict__ scale_ptr, float fscale,
             const float* __restrict__ addp, int ldadd) {
    __shared__ unsigned short Asl[128 * 64];
    __shared__ unsigned short Bsl[128 * 64];
    int bz = blockIdx.z;
    int batch = bz, sp = 0;
    if (nsplit > 1) { batch = bz / nsplit; sp = bz - batch * nsplit; }
    int m0 = blockIdx.y * 128, n0 = blockIdx.x * 128;
    const unsigned short* Ap = A + (long)batch * sA + (long)sp * K;
    const unsigned short* Bp = B + (long)batch * sB + (long)sp * K;
    int tid = threadIdx.x, lane = tid & 63, wave = tid >> 6;
    int wr = wave >> 1, wc = wave & 1;
    f32x4 acc[4][4] = {};
    for (int k0 = 0; k0 < K; k0 += 64) {
        #pragma unroll
        for (int cc = 0; cc < 4; ++cc) {
            int bu = (wave * 4 + cc) * 64;
            int uidx = bu + lane;
            int r = uidx >> 3, slot = uidx & 7;
            int gu = slot ^ (r & 7);
            gload_lds16(Ap + (long)(m0 + r) * lda + k0 + gu * 8, Asl + bu * 8);
        }
        #pragma unroll
        for (int cc = 0; cc < 4; ++cc) {
            int bu = (wave * 4 + cc) * 64;
            int uidx = bu + lane;
            int r = uidx >> 3, slot = uidx & 7;
            int gu = slot ^ (r & 7);
            gload_lds16(Bp + (long)(n0 + r) * ldb + k0 + gu * 8, Bsl + bu * 8);
        }
        __syncthreads();
        #pragma unroll
        for (int ksub = 0; ksub < 2; ++ksub) {
            short8 av[4], bv[4];
            #pragma unroll
            for (int m = 0; m < 4; ++m) {
                int r = wr * 64 + m * 16 + (lane & 15);
                int slot = (ksub * 4 + (lane >> 4)) ^ (r & 7);
                av[m] = *(const short8*)(Asl + r * 64 + slot * 8);
            }
            #pragma unroll
            for (int n = 0; n < 4; ++n) {
                int r = wc * 64 + n * 16 + (lane & 15);
                int slot = (ksub * 4 + (lane >> 4)) ^ (r & 7);
                bv[n] = *(const short8*)(Bsl + r * 64 + slot * 8);
            }
            #pragma unroll
            for (int m = 0; m < 4; ++m)
                #pragma unroll
                for (int n = 0; n < 4; ++n)
                    acc[m][n] = __builtin_amdgcn_mfma_f32_16x16x32_bf16(av[m], bv[n], acc[m][n], 0, 0, 0);
        }
        __syncthreads();
    }
    float s = fscale * (scale_ptr ? scale_ptr[0] : 1.0f);
    long cbase = (long)batch * sCi + (long)sp * sSplit;
    int row0 = m0 + wr * 64, col0 = n0 + wc * 64 + (lane & 15);
    int rbase = (lane >> 4) * 4;
    #pragma unroll
    for (int m = 0; m < 4; ++m)
        #pragma unroll
        for (int i = 0; i < 4; ++i) {
            long row = row0 + m * 16 + rbase + i;
            #pragma unroll
            for (int n = 0; n < 4; ++n) {
                long col = col0 + n * 16;
                float v = acc[m][n][i] * s;
                if (addp) v += addp[row * (long)ldadd + col];
                long idx = cbase + row * ldc + col;
                if (WRITE_BF16) ((unsigned short*)C)[idx] = f2bu(v);
                else ((float*)C)[idx] = v;
            }
        }
}

// ---------------- flash-decoding split: KVBLK=64, DPP softmax (r9-best structure) ----------------
// item = (bh, strip32, K-chunk of <=8 tiles); 160 items/bh, 5120 items in 1280 blocks.
__global__ __launch_bounds__(256)
void k_flash_split(const unsigned short* __restrict__ hq, const unsigned short* __restrict__ hk,
                   const unsigned short* __restrict__ hvT,
                   unsigned short* __restrict__ opart, float* __restrict__ mpart, float* __restrict__ lpart) {
    __shared__ unsigned short P_lds[4][32 * 72];
    int lane = threadIdx.x & 63, wave = threadIdx.x >> 6;
    unsigned short* P = P_lds[wave];
    int g = lane >> 4, c = lane & 15;
    unsigned bid = blockIdx.x;                           // 0..1279
    unsigned bswz = (bid & 7) * 160 + (bid >> 3);        // XCD-bijective: 160 blocks (=4 bh) per XCD
    unsigned gi = bswz * 4 + wave;                       // global item 0..5119
    unsigned bh = gi / 160, itr = gi % 160;
    int item = 159 - (int)itr;                           // longest chunks first
    int strip, chunk;
    if (item < 16)      { strip = item;                 chunk = 0; }
    else if (item < 48) { strip = 16 + (item - 16) / 2; chunk = (item - 16) & 1; }
    else if (item < 96) { strip = 32 + (item - 48) / 3; chunk = (item - 48) % 3; }
    else                { strip = 48 + (item - 96) / 4; chunk = (item - 96) & 3; }
    int q0 = strip * 32;
    int nt = (q0 + 32 + 63) >> 6;
    int ti0 = chunk * 8;
    int ti1 = ti0 + 8 < nt ? ti0 + 8 : nt;
    const unsigned short* qb = hq + (long)bh * Tc * 64;
    const unsigned short* kb = hk + (long)bh * Tc * 64;
    const unsigned short* vtb = hvT + (long)bh * 64 * Tc;

    short8 qf[2][2];
    #pragma unroll
    for (int mf = 0; mf < 2; ++mf)
        #pragma unroll
        for (int ks = 0; ks < 2; ++ks)
            qf[mf][ks] = *(const short8*)(qb + (long)(q0 + mf * 16 + c) * 64 + ks * 32 + g * 8);

    f32x4 o_acc[2][4] = {};
    float m_run[2][4], lpp[2][4];
    #pragma unroll
    for (int mf = 0; mf < 2; ++mf)
        #pragma unroll
        for (int i = 0; i < 4; ++i) { m_run[mf][i] = -3.0e38f; lpp[mf][i] = 0.f; }

    for (int ti = ti0; ti < ti1; ++ti) {
        int kt = ti * 64;
        // V loads issued early; latency overlaps K-wait + QK + softmax
        short8 vf[2][4];
        #pragma unroll
        for (int ks = 0; ks < 2; ++ks)
            #pragma unroll
            for (int df = 0; df < 4; ++df)
                vf[ks][df] = *(const short8*)(vtb + (long)(df * 16 + c) * Tc + kt + ks * 32 + g * 8);
        f32x4 s_acc[2][4] = {};
        #pragma unroll
        for (int ks = 0; ks < 2; ++ks) {
            short8 kf[4];
            #pragma unroll
            for (int nf = 0; nf < 4; ++nf)
                kf[nf] = *(const short8*)(kb + (long)(kt + nf * 16 + c) * 64 + ks * 32 + g * 8);
            #pragma unroll
            for (int mf = 0; mf < 2; ++mf)
                #pragma unroll
                for (int nf = 0; nf < 4; ++nf)
                    s_acc[mf][nf] = __builtin_amdgcn_mfma_f32_16x16x32_bf16(qf[mf][ks], kf[nf], s_acc[mf][nf], 0, 0, 0);
        }
        // causal mask: only the diagonal tile needs it
        if (ti == nt - 1) {
            #pragma unroll
            for (int mf = 0; mf < 2; ++mf)
                #pragma unroll
                for (int nf = 0; nf < 4; ++nf)
                    #pragma unroll
                    for (int i = 0; i < 4; ++i)
                        if ((kt + nf * 16 + c) > (q0 + mf * 16 + g * 4 + i)) s_acc[mf][nf][i] = -1.0e30f;
        }
        // raw-domain row max: in-lane over nf, then DPP tree over 16 lanes (VALU pipe)
        float pm[2][4];
        #pragma unroll
        for (int mf = 0; mf < 2; ++mf)
            #pragma unroll
            for (int i = 0; i < 4; ++i)
                pm[mf][i] = max16(fmaxf(fmaxf(s_acc[mf][0][i], s_acc[mf][1][i]),
                                        fmaxf(s_acc[mf][2][i], s_acc[mf][3][i])));
        // defer-max: rescale only if any row's scaled max grew beyond m_run + 8
        float mg = 0.f;
        #pragma unroll
        for (int mf = 0; mf < 2; ++mf)
            #pragma unroll
            for (int i = 0; i < 4; ++i) {
                pm[mf][i] *= 0.125f;
                mg = fmaxf(mg, pm[mf][i] - m_run[mf][i]);
            }
        if (__any(mg > 8.0f)) {
            #pragma unroll
            for (int mf = 0; mf < 2; ++mf)
                #pragma unroll
                for (int i = 0; i < 4; ++i) {
                    float mn = fmaxf(m_run[mf][i], pm[mf][i]);
                    float corr = __expf(m_run[mf][i] - mn);
                    m_run[mf][i] = mn;
                    lpp[mf][i] *= corr;
                    #pragma unroll
                    for (int df = 0; df < 4; ++df) o_acc[mf][df][i] *= corr;
                }
        }
        // exp (scale folded into fma) + P store + per-lane l accumulate
        #pragma unroll
        for (int mf = 0; mf < 2; ++mf)
            #pragma unroll
            for (int nf = 0; nf < 4; ++nf)
                #pragma unroll
                for (int i = 0; i < 4; ++i) {
                    float p = __expf(fmaf(s_acc[mf][nf][i], 0.125f, -m_run[mf][i]));
                    P[(mf * 16 + g * 4 + i) * 72 + nf * 16 + c] = f2bu(p);
                    lpp[mf][i] += p;
                }
        // PV
        #pragma unroll
        for (int ks = 0; ks < 2; ++ks) {
            short8 pa[2];
            #pragma unroll
            for (int mf = 0; mf < 2; ++mf)
                pa[mf] = *(const short8*)(P + (mf * 16 + c) * 72 + ks * 32 + g * 8);
            #pragma unroll
            for (int mf = 0; mf < 2; ++mf)
                #pragma unroll
                for (int df = 0; df < 4; ++df)
                    o_acc[mf][df] = __builtin_amdgcn_mfma_f32_16x16x32_bf16(pa[mf], vf[ks][df], o_acc[mf][df], 0, 0, 0);
        }
    }
    // one l-sum DPP tree for the whole chunk
    #pragma unroll
    for (int mf = 0; mf < 2; ++mf)
        #pragma unroll
        for (int i = 0; i < 4; ++i)
            lpp[mf][i] = sum16(lpp[mf][i]);
    long pbase = (long)(bh * 160 + item);
    #pragma unroll
    for (int mf = 0; mf < 2; ++mf)
        #pragma unroll
        for (int i = 0; i < 4; ++i) {
            int row_l = mf * 16 + g * 4 + i;
            #pragma unroll
            for (int df = 0; df < 4; ++df)
                opart[pbase * 2048 + row_l * 64 + df * 16 + c] = f2bu(o_acc[mf][df][i]);
            if (c == 0) {
                mpart[pbase * 32 + row_l] = m_run[mf][i];
                lpart[pbase * 32 + row_l] = lpp[mf][i];
            }
        }
}

// ---------------- flash merge: combine <=4 bf16 partials per (bh,strip) -> bf16 y ----------------
__global__ __launch_bounds__(256)
void k_flash_merge(const unsigned short* __restrict__ opart, const float* __restrict__ mpart,
                   const float* __restrict__ lpart, unsigned short* __restrict__ yout) {
    int bs = blockIdx.x;
    int bh = bs >> 6, strip = bs & 63;
    int b = bh >> 4, h = bh & 15;
    int np, base;
    if (strip < 16)      { np = 1; base = strip; }
    else if (strip < 32) { np = 2; base = 16 + (strip - 16) * 2; }
    else if (strip < 48) { np = 3; base = 48 + (strip - 32) * 3; }
    else                 { np = 4; base = 96 + (strip - 48) * 4; }
    long p0 = (long)(bh * 160 + base);
    int tid = threadIdx.x;
    int r = tid >> 3, c0 = (tid & 7) * 8;
    float M = -3.0e38f;
    for (int p = 0; p < np; ++p) M = fmaxf(M, mpart[(p0 + p) * 32 + r]);
    float L = 0.f;
    float acc[8] = {};
    for (int p = 0; p < np; ++p) {
        float sc = __expf(mpart[(p0 + p) * 32 + r] - M);
        L += lpart[(p0 + p) * 32 + r] * sc;
        const unsigned short* op = opart + (p0 + p) * 2048 + r * 64 + c0;
        ushort4 a = *(const ushort4*)op;
        ushort4 bq = *(const ushort4*)(op + 4);
        acc[0] += bu2f(a.x) * sc; acc[1] += bu2f(a.y) * sc;
        acc[2] += bu2f(a.z) * sc; acc[3] += bu2f(a.w) * sc;
        acc[4] += bu2f(bq.x) * sc; acc[5] += bu2f(bq.y) * sc;
        acc[6] += bu2f(bq.z) * sc; acc[7] += bu2f(bq.w) * sc;
    }
    float inv = 1.0f / L;
    long row = (long)b * Tc + strip * 32 + r;
    unsigned short* yp = yout + row * 1024 + h * 64 + c0;
    ushort4 o1, o2;
    o1.x = f2bu(acc[0] * inv); o1.y = f2bu(acc[1] * inv); o1.z = f2bu(acc[2] * inv); o1.w = f2bu(acc[3] * inv);
    o2.x = f2bu(acc[4] * inv); o2.y = f2bu(acc[5] * inv); o2.z = f2bu(acc[6] * inv); o2.w = f2bu(acc[7] * inv);
    *(ushort4*)yp = o1;
    *(ushort4*)(yp + 4) = o2;
}

// ---------------- AFT gated cumsum (bf16 qkv): 3-pass chunked ----------------
__global__ void k_aft_p1(const unsigned short* __restrict__ qkv, float* __restrict__ cw, float* __restrict__ cs) {
    int id = blockIdx.x * TPB + threadIdx.x;
    int bc = id & 2047, ch = id >> 11;
    int b = bc >> 10, c = bc & 1023;
    const unsigned short* base = qkv + ((long)(b * Tc + ch * CHL)) * 3072 + c;
    float sw = 0.f, sv = 0.f;
    for (int i = 0; i < CHL; ++i) {
        float k = bu2f(base[1024]), v = bu2f(base[2048]);
        float e = __expf(k);
        sw += e; sv += e * v;
        base += 3072;
    }
    cw[ch * 2048 + bc] = sw; cs[ch * 2048 + bc] = sv;
}

__global__ void k_aft_p2(float* __restrict__ cw, float* __restrict__ cs) {
    int bc = blockIdx.x * TPB + threadIdx.x;
    float rw = 0.f, rv = 0.f;
    for (int ch = 0; ch < NCH; ++ch) {
        long idx = (long)ch * 2048 + bc;
        float tw = cw[idx], tv = cs[idx];
        cw[idx] = rw; cs[idx] = rv; rw += tw; rv += tv;
    }
}

__global__ void k_aft_p3(const unsigned short* __restrict__ qkv, const float* __restrict__ cw,
                         const float* __restrict__ cs, unsigned short* __restrict__ y) {
    int id = blockIdx.x * TPB + threadIdx.x;
    int bc = id & 2047, ch = id >> 11;
    int b = bc >> 10, c = bc & 1023;
    float aw = cw[ch * 2048 + bc], av = cs[ch * 2048 + bc];
    long t0 = (long)b * Tc + ch * CHL;
    const unsigned short* base = qkv + t0 * 3072 + c;
    unsigned short* yp = y + t0 * 1024 + c;
    for (int i = 0; i < CHL; ++i) {
        float q = bu2f(base[0]), k = bu2f(base[1024]), v = bu2f(base[2048]);
        float e = __expf(k);
        av += e * v; aw += e;
        float sig = 1.0f / (1.0f + __expf(-q));
        yp[0] = f2bu(sig * av / (aw + 1e-6f));
        base += 3072; yp += 1024;
    }
}

// ---------------- fused u*silu(v) -> bf16 + rowrms(u), bf16 uv in (block per row) ----------------
__global__ void k_silu_rms(const unsigned short* __restrict__ uv, unsigned short* __restrict__ g,
                           float* __restrict__ rs) {
    __shared__ float red[TPB];
    long row = blockIdx.x;
    const unsigned short* up = uv + row * 2048;
    ushort4 u4 = *(const ushort4*)(up + threadIdx.x * 4);
    ushort4 v4 = *(const ushort4*)(up + 1024 + threadIdx.x * 4);
    float u0 = bu2f(u4.x), u1 = bu2f(u4.y), u2 = bu2f(u4.z), u3 = bu2f(u4.w);
    float v0 = bu2f(v4.x), v1 = bu2f(v4.y), v2 = bu2f(v4.z), v3 = bu2f(v4.w);
    ushort4 o;
    o.x = f2bu(u0 * v0 / (1.f + __expf(-v0)));
    o.y = f2bu(u1 * v1 / (1.f + __expf(-v1)));
    o.z = f2bu(u2 * v2 / (1.f + __expf(-v2)));
    o.w = f2bu(u3 * v3 / (1.f + __expf(-v3)));
    *(ushort4*)(g + row * 1024 + threadIdx.x * 4) = o;
    red[threadIdx.x] = u0 * u0 + u1 * u1 + u2 * u2 + u3 * u3;
    __syncthreads();
    for (int off = 128; off > 0; off >>= 1) {
        if (threadIdx.x < off) red[threadIdx.x] += red[threadIdx.x + off];
        __syncthreads();
    }
    if (threadIdx.x == 0) rs[row] = rsqrtf(red[0] / 1024.0f + F32_EPS);
}

// ---------------- u * silu(v) -> bf16 (final swiglu, bf16 in) ----------------
__global__ void k_silu_gate(const unsigned short* __restrict__ uv, unsigned short* __restrict__ g, long n4) {
    long i = (long)blockIdx.x * TPB + threadIdx.x;
    if (i >= n4) return;
    long r = i >> 8, c4 = i & 255;
    ushort4 u4 = *(const ushort4*)(uv + r * 2048 + c4 * 4);
    ushort4 v4 = *(const ushort4*)(uv + r * 2048 + 1024 + c4 * 4);
    float u0 = bu2f(u4.x), u1 = bu2f(u4.y), u2 = bu2f(u4.z), u3 = bu2f(u4.w);
    float v0 = bu2f(v4.x), v1 = bu2f(v4.y), v2 = bu2f(v4.z), v3 = bu2f(v4.w);
    ushort4 o;
    o.x = f2bu(u0 * v0 / (1.f + __expf(-v0)));
    o.y = f2bu(u1 * v1 / (1.f + __expf(-v1)));
    o.z = f2bu(u2 * v2 / (1.f + __expf(-v2)));
    o.w = f2bu(u3 * v3 / (1.f + __expf(-v3)));
    *(ushort4*)(g + r * 1024 + c4 * 4) = o;
}

// ---------------- w_out = p*s*silu(w_in) + w_in  (also emits bf16 copy) ----------------
__global__ void k_wupdate(float* __restrict__ wout, const float* __restrict__ win,
                          const float* __restrict__ p, const float* __restrict__ scale,
                          unsigned short* __restrict__ wb, long n4) {
    long i = (long)blockIdx.x * TPB + threadIdx.x;
    if (i >= n4) return;
    float s = scale[0];
    float4 wv = *(const float4*)(win + i * 4);
    float4 pv = *(const float4*)(p + i * 4);
    float4 o;
    o.x = pv.x * s * (wv.x / (1.f + __expf(-wv.x))) + wv.x;
    o.y = pv.y * s * (wv.y / (1.f + __expf(-wv.y))) + wv.y;
    o.z = pv.z * s * (wv.z / (1.f + __expf(-wv.z))) + wv.z;
    o.w = pv.w * s * (wv.w / (1.f + __expf(-wv.w))) + wv.w;
    *(float4*)(wout + i * 4) = o;
    ushort4 ob; ob.x = f2bu(o.x); ob.y = f2bu(o.y); ob.z = f2bu(o.z); ob.w = f2bu(o.w);
    *(ushort4*)(wb + i * 4) = ob;
}

// ---------------- 4-slab reduce + scale + row softmax -> fp32 out ----------------
__global__ void k_softmax4(const float* __restrict__ parts, float* __restrict__ outb, float fscale) {
    __shared__ float red[TPB];
    __shared__ float rowbuf[1024];
    long row = blockIdx.x;
    const float* p0 = parts + row * 1024;
    for (int c = threadIdx.x; c < 1024; c += TPB) {
        float v = p0[c] + p0[c + 1048576] + p0[c + 2097152] + p0[c + 3145728];
        rowbuf[c] = v * fscale;
    }
    __syncthreads();
    float m = -3.0e38f;
    for (int c = threadIdx.x; c < 1024; c += TPB) m = fmaxf(m, rowbuf[c]);
    red[threadIdx.x] = m; __syncthreads();
    for (int o = 128; o > 0; o >>= 1) {
        if (threadIdx.x < o) red[threadIdx.x] = fmaxf(red[threadIdx.x], red[threadIdx.x + o]);
        __syncthreads();
    }
    m = red[0]; __syncthreads();
    float sum = 0.f;
    for (int c = threadIdx.x; c < 1024; c += TPB) sum += __expf(rowbuf[c] - m);
    red[threadIdx.x] = sum; __syncthreads();
    for (int o = 128; o > 0; o >>= 1) {
        if (threadIdx.x < o) red[threadIdx.x] += red[threadIdx.x + o];
        __syncthreads();
    }
    float inv = 1.0f / red[0];
    for (int c = threadIdx.x; c < 1024; c += TPB)
        outb[row * 1024 + c] = __expf(rowbuf[c] - m) * inv;
}

// ---------------- tea: rotary + per-head rmsnorm + split, bf16 in/out ----------------
__global__ void k_rot_split(const unsigned short* __restrict__ qkvp, const float* __restrict__ cosp,
                            const float* __restrict__ sinp, unsigned short* __restrict__ hq,
                            unsigned short* __restrict__ hk, unsigned short* __restrict__ hv) {
    __shared__ float row[3072];
    __shared__ float cs[32], sn[32];
    int bt = blockIdx.x;
    int b = bt >> 11, t = bt & 2047;
    const unsigned short* src = qkvp + (long)bt * 3072;
    #pragma unroll
    for (int u = 0; u < 3; ++u) {
        int idx = threadIdx.x + u * 256;
        ushort4 v = *(const ushort4*)(src + idx * 4);
        row[idx * 4 + 0] = bu2f(v.x); row[idx * 4 + 1] = bu2f(v.y);
        row[idx * 4 + 2] = bu2f(v.z); row[idx * 4 + 3] = bu2f(v.w);
    }
    if (threadIdx.x < 32) { cs[threadIdx.x] = cosp[t * 32 + threadIdx.x]; sn[threadIdx.x] = sinp[t * 32 + threadIdx.x]; }
    __syncthreads();
    int h = threadIdx.x >> 4, li = threadIdx.x & 15;
    int base = h * 192;
    long obase = ((long)(b * Hc + h) * Tc + t) * 64 + li * 4;
    {
        float r[4]; float ss = 0.f;
        #pragma unroll
        for (int j = 0; j < 4; ++j) {
            int d = li * 4 + j;
            float val = (d < 32) ? (row[base + d] * cs[d] + row[base + d + 32] * sn[d])
                                 : (-row[base + d - 32] * sn[d - 32] + row[base + d] * cs[d - 32]);
            r[j] = val; ss += val * val;
        }
        ss = sum16(ss);
        float sc = rsqrtf(ss / 64.0f + F32_EPS);
        ushort4 o; o.x = f2bu(r[0] * sc); o.y = f2bu(r[1] * sc); o.z = f2bu(r[2] * sc); o.w = f2bu(r[3] * sc);
        *(ushort4*)(hq + obase) = o;
    }
    {
        int kb = base + 64;
        float r[4]; float ss = 0.f;
        #pragma unroll
        for (int j = 0; j < 4; ++j) {
            int d = li * 4 + j;
            float val = (d < 32) ? (row[kb + d] * cs[d] + row[kb + d + 32] * sn[d])
                                 : (-row[kb + d - 32] * sn[d - 32] + row[kb + d] * cs[d - 32]);
            r[j] = val; ss += val * val;
        }
        ss = sum16(ss);
        float sc = rsqrtf(ss / 64.0f + F32_EPS);
        ushort4 o; o.x = f2bu(r[0] * sc); o.y = f2bu(r[1] * sc); o.z = f2bu(r[2] * sc); o.w = f2bu(r[3] * sc);
        *(ushort4*)(hk + obase) = o;
    }
    {
        ushort4 o;
        o.x = f2bu(row[base + 128 + li * 4 + 0]); o.y = f2bu(row[base + 128 + li * 4 + 1]);
        o.z = f2bu(row[base + 128 + li * 4 + 2]); o.w = f2bu(row[base + 128 + li * 4 + 3]);
        *(ushort4*)(hv + obase) = o;
    }
}

extern "C" void kernel_launch(void* const* d_in, const int* in_sizes, int n_in,
                              void* d_out, int out_size, void* d_ws, size_t ws_size,
                              hipStream_t stream) {
    const float* x_in = (const float*)d_in[0];
    const float* w_in = (const float*)d_in[1];
    const float* cos_in = (const float*)d_in[2];
    const float* sin_in = (const float*)d_in[3];
    float* out = (float*)d_out;
    float* ws = (float*)d_ws;

    long off = 0;
    float* w_cur = ws + off;  off += (long)WR * Ec;
    float* w_tmp = ws + off;  off += (long)WR * Ec;   // also: oa split-K partials (4M floats)
    float* xbuf  = ws + off;  off += BT * Ec;
    float* R     = ws + off;  off += BT * 3L * QKVc;  // bf16 qkvb+uvb | bf16 opart | split-K slabs
    float* oab   = ws + off;  off += (long)Ec * Ec;   // also: flash m/l partials
    float* red   = ws + off;  off += 2048;
    float* scales= ws + off;  off += 16;
    float* uscale= ws + off;  off += 4096;
    float* chw   = ws + off;  off += 2048L * NCH;
    float* chs   = ws + off;  off += 2048L * NCH;
    unsigned short* qkvb  = (unsigned short*)R;          // 12.58M ushorts
    unsigned short* uvb   = qkvb + 12582912L;            // 8.39M ushorts
    unsigned short* opartb= qkvb;                         // final-phase alias
    unsigned short* wsplit = qkvb;                        // w@oa split slabs (2 x 6.29M) - qkv dead
    unsigned short* osplit = uvb;                         // out-proj split slabs (2 x 4.19M) - uv dead
    float* mpart = oab;
    float* lpart = oab + 5120L * 32;

    unsigned short* bp = (unsigned short*)(ws + off);
    long bo = 0;
    unsigned short* wb  = bp + bo; bo += (long)WR * Ec;
    unsigned short* xbn = bp + bo; bo += BT * Ec;
    unsigned short* ybn = bp + bo; bo += BT * Ec;
    unsigned short* gbn = bp + bo; bo += BT * Ec;
    unsigned short* t1  = bp + bo; bo += BT * Ec;            // o^T | hq
    unsigned short* t2  = bp + bo; bo += BT * Ec;            // v^T | hk
    unsigned short* t3  = bp + bo; bo += BT * Ec;            // oa^T | hvS
    unsigned short* t4  = bp + bo; bo += BT * Ec;            // hvT

    const float rsWR = 1.0f / sqrtf(6144.0f);
    const long wsw = 3072L * 1024, wout = 5120L * 1024;

    // one-time bf16 copy of w (from input)
    k_cast_bf16<<<(int)(((long)WR * Ec / 4) / TPB), TPB, 0, stream>>>(w_in, wb, (long)WR * Ec / 4);

    for (int layer = 0; layer < 2; ++layer) {
        const float* wsrc = layer == 0 ? w_in : w_cur;   // fp32 weights
        const float* xsrc = layer == 0 ? x_in : xbuf;    // fp32 activations
        k_std_partial3<<<dim3(256, 3), TPB, 0, stream>>>(wsrc, red);
        k_std_final3<<<1, TPB, 0, stream>>>(red, scales);
        k_rms1024b<<<BT, TPB, 0, stream>>>(xsrc, xbn, 1024, 1024);
        k_bgemm<1><<<dim3(24, 32, 1), TPB, 0, stream>>>(
            1024, xbn, 1024, 0, wb, 1024, 0, qkvb, 3072, 0, 0, 1, scales + 0, 1.0f, nullptr, 0);
        k_rms_qk<<<8192, TPB, 0, stream>>>(qkvb);
        k_aft_p1<<<(2048 * NCH) / TPB, TPB, 0, stream>>>(qkvb, chw, chs);
        k_aft_p2<<<2048 / TPB, TPB, 0, stream>>>(chw, chs);
        k_aft_p3<<<(2048 * NCH) / TPB, TPB, 0, stream>>>(qkvb, chw, chs, ybn);
        k_bgemm<1><<<dim3(16, 32, 1), TPB, 0, stream>>>(
            1024, ybn, 1024, 0, wb + wsw, 1024, 0, uvb, 2048, 0, 0, 1, scales + 1, 1.0f, nullptr, 0);
        k_silu_rms<<<BT, TPB, 0, stream>>>(uvb, gbn, uscale);
        k_tcast2<<<dim3(16, 64, 2), TPB, 0, stream>>>(uvb, uscale, t1, t2);
        // oa = softmax(o^T @ a * E^-0.5), split-K x4 into w_tmp partials
        k_bgemm<0><<<dim3(8, 8, 4), TPB, 0, stream>>>(
            1024, t1, 4096, 0, t2, 4096, 0, w_tmp, 1024, 0, 1048576L, 4, nullptr, 1.0f, nullptr, 0);
        k_softmax4<<<1024, TPB, 0, stream>>>(w_tmp, oab, 0.03125f);
        k_tcast<float><<<dim3(16, 16, 1), TPB, 0, stream>>>(oab, 1024, 0, t3, 1024, 0, nullptr);
        // x' = x + g @ w_out^T * s2 : split-K x2 (bf16 partials in dead uv region) + merge
        k_bgemm<1><<<dim3(8, 32, 2), TPB, 0, stream>>>(
            512, gbn, 1024, 0, wb + wout, 1024, 0, osplit, 1024, 0, 4194304L, 2, scales + 2, 1.0f, nullptr, 0);
        k_merge2<<<(int)((BT * 1024 / 4) / TPB), TPB, 0, stream>>>(
            osplit, osplit + 4194304L, xsrc, xbuf, BT * 1024 / 4);
        // w_tmp = w @ oa : split-K x2 (bf16 partials in dead qkv region) + merge
        k_bgemm<1><<<dim3(8, 48, 2), TPB, 0, stream>>>(
            512, wb, 1024, 0, t3, 1024, 0, wsplit, 1024, 0, 6291456L, 2, nullptr, 1.0f, nullptr, 0);
        k_merge2<<<(int)(((long)WR * 1024 / 4) / TPB), TPB, 0, stream>>>(
            wsplit, wsplit + 6291456L, nullptr, w_tmp, (long)WR * 1024 / 4);
        k_std_partial<<<256, TPB, 0, stream>>>(w_tmp, (long)WR * 1024, red);
        k_std_final<<<1, TPB, 0, stream>>>(red, (float)((long)WR * 1024), rsWR, scales + 3);
        k_wupdate<<<(int)(((long)WR * 1024 / 4) / TPB), TPB, 0, stream>>>(
            w_cur, wsrc, w_tmp, scales + 3, wb, (long)WR * 1024 / 4);
    }

    // -------- final tea (no w_norm) --------
    k_rms1024b<<<BT, TPB, 0, stream>>>(xbuf, xbn, 1024, 1024);
    k_bgemm<1><<<dim3(24, 32, 1), TPB, 0, stream>>>(
        1024, xbn, 1024, 0, wb, 1024, 0, qkvb, 3072, 0, 0, 1, nullptr, 1.0f, nullptr, 0);
    k_rot_split<<<BT, TPB, 0, stream>>>(qkvb, cos_in, sin_in, t1, t2, t3);
    k_tcast<unsigned short><<<dim3(1, 32, 32), TPB, 0, stream>>>(
        t3, 64, (long)Tc * 64, t4, 2048, (long)Tc * 64, nullptr);
    // flash-decoding: 5120 items in 1280 blocks (4 waves/block, independent), then merge
    k_flash_split<<<dim3(1280), TPB, 0, stream>>>(t1, t2, t4, opartb, mpart, lpart);
    k_flash_merge<<<dim3(2048), TPB, 0, stream>>>(opartb, mpart, lpart, ybn);
    // final swiglu -> d_out
    k_bgemm<1><<<dim3(16, 32, 1), TPB, 0, stream>>>(
        1024, ybn, 1024, 0, wb + wsw, 1024, 0, uvb, 2048, 0, 0, 1, nullptr, 1.0f, nullptr, 0);
    k_silu_gate<<<(int)((BT * 1024 / 4) / TPB), TPB, 0, stream>>>(uvb, gbn, BT * 1024 / 4);
    // final out-proj: split-K x2 into dead qkvb region + merge(+x residual) -> out
    k_bgemm<1><<<dim3(8, 32, 2), TPB, 0, stream>>>(
        512, gbn, 1024, 0, wb + wout, 1024, 0, qkvb, 1024, 0, 4194304L, 2, nullptr, 1.0f, nullptr, 0);
    k_merge2<<<(int)((BT * 1024 / 4) / TPB), TPB, 0, stream>>>(
        qkvb, qkvb + 4194304L, xbuf, out, BT * 1024 / 4);
}

// Round 14
// 734.400 us; speedup vs baseline: 1.1778x; 1.0564x over previous
//
#include <hip/hip_runtime.h>
#include <hip/hip_bf16.h>
#include <math.h>

#define TPB 256

constexpr int Bc = 2, Tc = 2048, Ec = 1024, QKVc = 1024, Hc = 16, DHc = 64;
constexpr long BT = (long)Bc * Tc;     // 4096
constexpr int WR = 5 * QKVc + Ec;      // 6144
constexpr float F32_EPS = 1.1920928955078125e-07f;
constexpr int NCH = 64, CHL = Tc / NCH;

typedef __attribute__((ext_vector_type(8))) short short8;
typedef __attribute__((ext_vector_type(4))) float f32x4;

__device__ __forceinline__ unsigned short f2bu(float f) {
    union { __hip_bfloat16 h; unsigned short u; } c; c.h = __float2bfloat16(f); return c.u;
}
__device__ __forceinline__ float bu2f(unsigned short u) {
    union { __hip_bfloat16 h; unsigned short u; } c; c.u = u; return __bfloat162float(c.h);
}
__device__ __forceinline__ float ldval(const float* p) { return *p; }
__device__ __forceinline__ float ldval(const unsigned short* p) { return bu2f(*p); }

__device__ __forceinline__ void gload_lds16(const void* g, void* l) {
    __builtin_amdgcn_global_load_lds((const __attribute__((address_space(1))) void*)g,
                                     (__attribute__((address_space(3))) void*)l, 16, 0, 0);
}

// ---- DPP cross-lane (VALU pipe): reduce over 16-lane groups ----
template<int CTRL>
__device__ __forceinline__ float dppf(float x) {
    union { float f; int i; } a, b;
    a.f = x;
    b.i = __builtin_amdgcn_update_dpp(0, a.i, CTRL, 0xF, 0xF, true);
    return b.f;
}
__device__ __forceinline__ float max16(float v) {
    v = fmaxf(v, dppf<0xB1>(v));
    v = fmaxf(v, dppf<0x4E>(v));
    v = fmaxf(v, dppf<0x124>(v));
    v = fmaxf(v, dppf<0x128>(v));
    return v;
}
__device__ __forceinline__ float sum16(float v) {
    v += dppf<0xB1>(v);
    v += dppf<0x4E>(v);
    v += dppf<0x124>(v);
    v += dppf<0x128>(v);
    return v;
}

// ---------------- fused 3-segment global std (ddof=1) for w_qkv/w_sw/w_out ----------------
__global__ void k_std_partial3(const float* __restrict__ w, float* __restrict__ out) {
    __shared__ float ls[TPB], lss[TPB];
    int seg = blockIdx.y;
    long base = (seg == 0) ? 0L : (seg == 1 ? 3072L * 1024 : 5120L * 1024);
    long n    = (seg == 0) ? 3072L * 1024 : (seg == 1 ? 2048L * 1024 : 1024L * 1024);
    const float* p = w + base;
    float s = 0.f, ss = 0.f;
    for (long i = (long)blockIdx.x * TPB + threadIdx.x; i < n; i += 256L * TPB) {
        float v = p[i]; s += v; ss += v * v;
    }
    ls[threadIdx.x] = s; lss[threadIdx.x] = ss; __syncthreads();
    for (int o = 128; o > 0; o >>= 1) {
        if (threadIdx.x < o) { ls[threadIdx.x] += ls[threadIdx.x + o]; lss[threadIdx.x] += lss[threadIdx.x + o]; }
        __syncthreads();
    }
    if (threadIdx.x == 0) { out[seg * 512 + blockIdx.x] = ls[0]; out[seg * 512 + 256 + blockIdx.x] = lss[0]; }
}

__global__ void k_std_final3(const float* __restrict__ part, float* __restrict__ scales) {
    __shared__ float ls[TPB], lss[TPB];
    for (int seg = 0; seg < 3; ++seg) {
        ls[threadIdx.x] = part[seg * 512 + threadIdx.x];
        lss[threadIdx.x] = part[seg * 512 + 256 + threadIdx.x];
        __syncthreads();
        for (int o = 128; o > 0; o >>= 1) {
            if (threadIdx.x < o) { ls[threadIdx.x] += ls[threadIdx.x + o]; lss[threadIdx.x] += lss[threadIdx.x + o]; }
            __syncthreads();
        }
        if (threadIdx.x == 0) {
            float n = (seg == 0) ? 3145728.0f : (seg == 1 ? 2097152.0f : 1048576.0f);
            float var = (lss[0] - ls[0] * ls[0] / n) / (n - 1.0f);
            scales[seg] = 0.03125f / (sqrtf(fmaxf(var, 0.0f)) + 1e-8f);
        }
        __syncthreads();
    }
}

// ---------------- big std final: reduce 6144 per-block partials -> scale ----------------
__global__ void k_std_finalB(const float* __restrict__ red, float n, float rs, float* __restrict__ scale) {
    __shared__ float ls[TPB], lss[TPB];
    float s = 0.f, ss = 0.f;
    for (int i = threadIdx.x; i < 6144; i += TPB) { s += red[i]; ss += red[8192 + i]; }
    ls[threadIdx.x] = s; lss[threadIdx.x] = ss; __syncthreads();
    for (int o = 128; o > 0; o >>= 1) {
        if (threadIdx.x < o) { ls[threadIdx.x] += ls[threadIdx.x + o]; lss[threadIdx.x] += lss[threadIdx.x + o]; }
        __syncthreads();
    }
    if (threadIdx.x == 0) {
        float var = (lss[0] - ls[0] * ls[0] / n) / (n - 1.0f);
        scale[0] = rs / (sqrtf(fmaxf(var, 0.0f)) + 1e-8f);
    }
}

// ---------------- in-place rmsnorm of q and k halves of bf16 qkv (grid 8192) ----------------
__global__ void k_rms_qk(unsigned short* __restrict__ qkv) {
    __shared__ float red[TPB];
    int bid = blockIdx.x;
    long row = bid >> 1; int half = bid & 1;
    unsigned short* p = qkv + row * 3072 + half * 1024;
    ushort4 v = *(const ushort4*)(p + threadIdx.x * 4);
    float f0 = bu2f(v.x), f1 = bu2f(v.y), f2 = bu2f(v.z), f3 = bu2f(v.w);
    red[threadIdx.x] = f0 * f0 + f1 * f1 + f2 * f2 + f3 * f3;
    __syncthreads();
    for (int o = 128; o > 0; o >>= 1) {
        if (threadIdx.x < o) red[threadIdx.x] += red[threadIdx.x + o];
        __syncthreads();
    }
    float sc = rsqrtf(red[0] / 1024.0f + F32_EPS);
    ushort4 o4; o4.x = f2bu(f0 * sc); o4.y = f2bu(f1 * sc); o4.z = f2bu(f2 * sc); o4.w = f2bu(f3 * sc);
    *(ushort4*)(p + threadIdx.x * 4) = o4;
}

// ---------------- rmsnorm over 1024 cols, fp32 in -> bf16 out (layer 0 only) ----------------
__global__ void k_rms1024b(const float* __restrict__ in, unsigned short* __restrict__ out, long ldin, long ldout) {
    __shared__ float red[TPB];
    long row = blockIdx.x;
    float4 v = *(const float4*)(in + row * ldin + threadIdx.x * 4);
    float ss = v.x * v.x + v.y * v.y + v.z * v.z + v.w * v.w;
    red[threadIdx.x] = ss; __syncthreads();
    for (int o = 128; o > 0; o >>= 1) {
        if (threadIdx.x < o) red[threadIdx.x] += red[threadIdx.x + o];
        __syncthreads();
    }
    float sc = rsqrtf(red[0] / 1024.0f + F32_EPS);
    ushort4 o4; o4.x = f2bu(v.x * sc); o4.y = f2bu(v.y * sc); o4.z = f2bu(v.z * sc); o4.w = f2bu(v.w * sc);
    *(ushort4*)(out + row * ldout + threadIdx.x * 4) = o4;
}

// ---------------- fp32 -> bf16 cast ----------------
__global__ void k_cast_bf16(const float* __restrict__ in, unsigned short* __restrict__ out, long n4) {
    long i = (long)blockIdx.x * TPB + threadIdx.x;
    if (i >= n4) return;
    float4 v = *(const float4*)(in + i * 4);
    ushort4 o; o.x = f2bu(v.x); o.y = f2bu(v.y); o.z = f2bu(v.z); o.w = f2bu(v.w);
    *(ushort4*)(out + i * 4) = o;
}

// ---------------- merge 2 bf16 split-K slabs -> fp32 (+opt residual) ----------------
__global__ void k_merge2(const unsigned short* __restrict__ p0, const unsigned short* __restrict__ p1,
                         const float* __restrict__ resid, float* __restrict__ outp, long n4) {
    long i = (long)blockIdx.x * TPB + threadIdx.x;
    if (i >= n4) return;
    ushort4 a = *(const ushort4*)(p0 + i * 4);
    ushort4 b = *(const ushort4*)(p1 + i * 4);
    float4 o;
    o.x = bu2f(a.x) + bu2f(b.x); o.y = bu2f(a.y) + bu2f(b.y);
    o.z = bu2f(a.z) + bu2f(b.z); o.w = bu2f(a.w) + bu2f(b.w);
    if (resid) {
        float4 r = *(const float4*)(resid + i * 4);
        o.x += r.x; o.y += r.y; o.z += r.z; o.w += r.w;
    }
    *(float4*)(outp + i * 4) = o;
}

// ---------------- merge 2 slabs + residual + rmsnorm: writes fp32 x and bf16 rms(x) ----------------
__global__ void k_merge2rms(const unsigned short* __restrict__ p0, const unsigned short* __restrict__ p1,
                            const float* __restrict__ resid, float* __restrict__ xout,
                            unsigned short* __restrict__ xbn) {
    __shared__ float red[TPB];
    long row = blockIdx.x;
    long i = row * 256 + threadIdx.x;
    ushort4 a = *(const ushort4*)(p0 + i * 4);
    ushort4 b = *(const ushort4*)(p1 + i * 4);
    float4 r = *(const float4*)(resid + i * 4);
    float4 o;
    o.x = bu2f(a.x) + bu2f(b.x) + r.x; o.y = bu2f(a.y) + bu2f(b.y) + r.y;
    o.z = bu2f(a.z) + bu2f(b.z) + r.z; o.w = bu2f(a.w) + bu2f(b.w) + r.w;
    *(float4*)(xout + i * 4) = o;
    red[threadIdx.x] = o.x * o.x + o.y * o.y + o.z * o.z + o.w * o.w;
    __syncthreads();
    for (int off = 128; off > 0; off >>= 1) {
        if (threadIdx.x < off) red[threadIdx.x] += red[threadIdx.x + off];
        __syncthreads();
    }
    float sc = rsqrtf(red[0] / 1024.0f + F32_EPS);
    ushort4 ob; ob.x = f2bu(o.x * sc); ob.y = f2bu(o.y * sc); ob.z = f2bu(o.z * sc); ob.w = f2bu(o.w * sc);
    *(ushort4*)(xbn + i * 4) = ob;
}

// ---------------- merge 2 slabs -> fp32 + per-block sum/ssq partials ----------------
__global__ void k_merge2stat(const unsigned short* __restrict__ p0, const unsigned short* __restrict__ p1,
                             float* __restrict__ outp, float* __restrict__ red) {
    __shared__ float ls[TPB], lss[TPB];
    long i = (long)blockIdx.x * TPB + threadIdx.x;
    ushort4 a = *(const ushort4*)(p0 + i * 4);
    ushort4 b = *(const ushort4*)(p1 + i * 4);
    float4 o;
    o.x = bu2f(a.x) + bu2f(b.x); o.y = bu2f(a.y) + bu2f(b.y);
    o.z = bu2f(a.z) + bu2f(b.z); o.w = bu2f(a.w) + bu2f(b.w);
    *(float4*)(outp + i * 4) = o;
    ls[threadIdx.x] = o.x + o.y + o.z + o.w;
    lss[threadIdx.x] = o.x * o.x + o.y * o.y + o.z * o.z + o.w * o.w;
    __syncthreads();
    for (int off = 128; off > 0; off >>= 1) {
        if (threadIdx.x < off) { ls[threadIdx.x] += ls[threadIdx.x + off]; lss[threadIdx.x] += lss[threadIdx.x + off]; }
        __syncthreads();
    }
    if (threadIdx.x == 0) { red[blockIdx.x] = ls[0]; red[8192 + blockIdx.x] = lss[0]; }
}

// ---------------- transpose-cast: in[R][C] (ld, opt rowscale) -> bf16 out[C][R] ----------------
template<typename TI>
__global__ void k_tcast(const TI* __restrict__ in, long ldi, long sIn,
                        unsigned short* __restrict__ out, long ldo, long sOut,
                        const float* __restrict__ rowscale) {
    __shared__ float tile[64][65];
    const TI* ip = in + (long)blockIdx.z * sIn;
    unsigned short* op = out + (long)blockIdx.z * sOut;
    int r0 = blockIdx.y * 64, c0 = blockIdx.x * 64;
    int tid = threadIdx.x;
    int rr = tid >> 4, cc = (tid & 15) * 4;
    #pragma unroll
    for (int u = 0; u < 4; ++u) {
        int r = rr + u * 16;
        float sc = rowscale ? rowscale[r0 + r] : 1.0f;
        #pragma unroll
        for (int j = 0; j < 4; ++j)
            tile[r][cc + j] = ldval(ip + (long)(r0 + r) * ldi + c0 + cc + j) * sc;
    }
    __syncthreads();
    #pragma unroll
    for (int u = 0; u < 4; ++u) {
        int c = rr + u * 16;
        ushort4 o;
        o.x = f2bu(tile[cc + 0][c]); o.y = f2bu(tile[cc + 1][c]);
        o.z = f2bu(tile[cc + 2][c]); o.w = f2bu(tile[cc + 3][c]);
        *(ushort4*)(op + (long)(c0 + c) * ldo + r0 + cc) = o;
    }
}

// ---------------- fused transpose of o (rowscaled) and a from packed bf16 uv ----------------
__global__ void k_tcast2(const unsigned short* __restrict__ uv, const float* __restrict__ uscale,
                         unsigned short* __restrict__ t1, unsigned short* __restrict__ t2) {
    __shared__ float tile[64][65];
    int z = blockIdx.z;
    const unsigned short* ip = uv + (z ? 1024 : 0);
    unsigned short* op = z ? t2 : t1;
    int r0 = blockIdx.y * 64, c0 = blockIdx.x * 64;
    int tid = threadIdx.x;
    int rr = tid >> 4, cc = (tid & 15) * 4;
    #pragma unroll
    for (int u = 0; u < 4; ++u) {
        int r = rr + u * 16;
        float sc = z ? 1.0f : uscale[r0 + r];
        ushort4 v = *(const ushort4*)(ip + (long)(r0 + r) * 2048 + c0 + cc);
        tile[r][cc + 0] = bu2f(v.x) * sc; tile[r][cc + 1] = bu2f(v.y) * sc;
        tile[r][cc + 2] = bu2f(v.z) * sc; tile[r][cc + 3] = bu2f(v.w) * sc;
    }
    __syncthreads();
    #pragma unroll
    for (int u = 0; u < 4; ++u) {
        int c = rr + u * 16;
        ushort4 o;
        o.x = f2bu(tile[cc + 0][c]); o.y = f2bu(tile[cc + 1][c]);
        o.z = f2bu(tile[cc + 2][c]); o.w = f2bu(tile[cc + 3][c]);
        *(ushort4*)(op + (long)(c0 + c) * 4096 + r0 + cc) = o;
    }
}

// ---------------- bf16 MFMA GEMM, NT, 128x128 tile, BK=64 ----------------
template<int WRITE_BF16>
__global__ __launch_bounds__(256)
void k_bgemm(int K,
             const unsigned short* __restrict__ A, int lda, long sA,
             const unsigned short* __restrict__ B, int ldb, long sB,
             void* __restrict__ C, int ldc, long sCi, long sSplit, int nsplit,
             const float* __restrict__ scale_ptr, float fscale,
             const float* __restrict__ addp, int ldadd) {
    __shared__ unsigned short Asl[128 * 64];
    __shared__ unsigned short Bsl[128 * 64];
    int bz = blockIdx.z;
    int batch = bz, sp = 0;
    if (nsplit > 1) { batch = bz / nsplit; sp = bz - batch * nsplit; }
    int m0 = blockIdx.y * 128, n0 = blockIdx.x * 128;
    const unsigned short* Ap = A + (long)batch * sA + (long)sp * K;
    const unsigned short* Bp = B + (long)batch * sB + (long)sp * K;
    int tid = threadIdx.x, lane = tid & 63, wave = tid >> 6;
    int wr = wave >> 1, wc = wave & 1;
    f32x4 acc[4][4] = {};
    for (int k0 = 0; k0 < K; k0 += 64) {
        #pragma unroll
        for (int cc = 0; cc < 4; ++cc) {
            int bu = (wave * 4 + cc) * 64;
            int uidx = bu + lane;
            int r = uidx >> 3, slot = uidx & 7;
            int gu = slot ^ (r & 7);
            gload_lds16(Ap + (long)(m0 + r) * lda + k0 + gu * 8, Asl + bu * 8);
        }
        #pragma unroll
        for (int cc = 0; cc < 4; ++cc) {
            int bu = (wave * 4 + cc) * 64;
            int uidx = bu + lane;
            int r = uidx >> 3, slot = uidx & 7;
            int gu = slot ^ (r & 7);
            gload_lds16(Bp + (long)(n0 + r) * ldb + k0 + gu * 8, Bsl + bu * 8);
        }
        __syncthreads();
        #pragma unroll
        for (int ksub = 0; ksub < 2; ++ksub) {
            short8 av[4], bv[4];
            #pragma unroll
            for (int m = 0; m < 4; ++m) {
                int r = wr * 64 + m * 16 + (lane & 15);
                int slot = (ksub * 4 + (lane >> 4)) ^ (r & 7);
                av[m] = *(const short8*)(Asl + r * 64 + slot * 8);
            }
            #pragma unroll
            for (int n = 0; n < 4; ++n) {
                int r = wc * 64 + n * 16 + (lane & 15);
                int slot = (ksub * 4 + (lane >> 4)) ^ (r & 7);
                bv[n] = *(const short8*)(Bsl + r * 64 + slot * 8);
            }
            #pragma unroll
            for (int m = 0; m < 4; ++m)
                #pragma unroll
                for (int n = 0; n < 4; ++n)
                    acc[m][n] = __builtin_amdgcn_mfma_f32_16x16x32_bf16(av[m], bv[n], acc[m][n], 0, 0, 0);
        }
        __syncthreads();
    }
    float s = fscale * (scale_ptr ? scale_ptr[0] : 1.0f);
    long cbase = (long)batch * sCi + (long)sp * sSplit;
    int row0 = m0 + wr * 64, col0 = n0 + wc * 64 + (lane & 15);
    int rbase = (lane >> 4) * 4;
    #pragma unroll
    for (int m = 0; m < 4; ++m)
        #pragma unroll
        for (int i = 0; i < 4; ++i) {
            long row = row0 + m * 16 + rbase + i;
            #pragma unroll
            for (int n = 0; n < 4; ++n) {
                long col = col0 + n * 16;
                float v = acc[m][n][i] * s;
                if (addp) v += addp[row * (long)ldadd + col];
                long idx = cbase + row * ldc + col;
                if (WRITE_BF16) ((unsigned short*)C)[idx] = f2bu(v);
                else ((float*)C)[idx] = v;
            }
        }
}

// ---------------- flash-decoding split: KVBLK=64, DPP softmax (r9-best structure) ----------------
__global__ __launch_bounds__(256)
void k_flash_split(const unsigned short* __restrict__ hq, const unsigned short* __restrict__ hk,
                   const unsigned short* __restrict__ hvT,
                   unsigned short* __restrict__ opart, float* __restrict__ mpart, float* __restrict__ lpart) {
    __shared__ unsigned short P_lds[4][32 * 72];
    int lane = threadIdx.x & 63, wave = threadIdx.x >> 6;
    unsigned short* P = P_lds[wave];
    int g = lane >> 4, c = lane & 15;
    unsigned bid = blockIdx.x;
    unsigned bswz = (bid & 7) * 160 + (bid >> 3);
    unsigned gi = bswz * 4 + wave;
    unsigned bh = gi / 160, itr = gi % 160;
    int item = 159 - (int)itr;
    int strip, chunk;
    if (item < 16)      { strip = item;                 chunk = 0; }
    else if (item < 48) { strip = 16 + (item - 16) / 2; chunk = (item - 16) & 1; }
    else if (item < 96) { strip = 32 + (item - 48) / 3; chunk = (item - 48) % 3; }
    else                { strip = 48 + (item - 96) / 4; chunk = (item - 96) & 3; }
    int q0 = strip * 32;
    int nt = (q0 + 32 + 63) >> 6;
    int ti0 = chunk * 8;
    int ti1 = ti0 + 8 < nt ? ti0 + 8 : nt;
    const unsigned short* qb = hq + (long)bh * Tc * 64;
    const unsigned short* kb = hk + (long)bh * Tc * 64;
    const unsigned short* vtb = hvT + (long)bh * 64 * Tc;

    short8 qf[2][2];
    #pragma unroll
    for (int mf = 0; mf < 2; ++mf)
        #pragma unroll
        for (int ks = 0; ks < 2; ++ks)
            qf[mf][ks] = *(const short8*)(qb + (long)(q0 + mf * 16 + c) * 64 + ks * 32 + g * 8);

    f32x4 o_acc[2][4] = {};
    float m_run[2][4], lpp[2][4];
    #pragma unroll
    for (int mf = 0; mf < 2; ++mf)
        #pragma unroll
        for (int i = 0; i < 4; ++i) { m_run[mf][i] = -3.0e38f; lpp[mf][i] = 0.f; }

    for (int ti = ti0; ti < ti1; ++ti) {
        int kt = ti * 64;
        short8 vf[2][4];
        #pragma unroll
        for (int ks = 0; ks < 2; ++ks)
            #pragma unroll
            for (int df = 0; df < 4; ++df)
                vf[ks][df] = *(const short8*)(vtb + (long)(df * 16 + c) * Tc + kt + ks * 32 + g * 8);
        f32x4 s_acc[2][4] = {};
        #pragma unroll
        for (int ks = 0; ks < 2; ++ks) {
            short8 kf[4];
            #pragma unroll
            for (int nf = 0; nf < 4; ++nf)
                kf[nf] = *(const short8*)(kb + (long)(kt + nf * 16 + c) * 64 + ks * 32 + g * 8);
            #pragma unroll
            for (int mf = 0; mf < 2; ++mf)
                #pragma unroll
                for (int nf = 0; nf < 4; ++nf)
                    s_acc[mf][nf] = __builtin_amdgcn_mfma_f32_16x16x32_bf16(qf[mf][ks], kf[nf], s_acc[mf][nf], 0, 0, 0);
        }
        if (ti == nt - 1) {
            #pragma unroll
            for (int mf = 0; mf < 2; ++mf)
                #pragma unroll
                for (int nf = 0; nf < 4; ++nf)
                    #pragma unroll
                    for (int i = 0; i < 4; ++i)
                        if ((kt + nf * 16 + c) > (q0 + mf * 16 + g * 4 + i)) s_acc[mf][nf][i] = -1.0e30f;
        }
        float pm[2][4];
        #pragma unroll
        for (int mf = 0; mf < 2; ++mf)
            #pragma unroll
            for (int i = 0; i < 4; ++i)
                pm[mf][i] = max16(fmaxf(fmaxf(s_acc[mf][0][i], s_acc[mf][1][i]),
                                        fmaxf(s_acc[mf][2][i], s_acc[mf][3][i])));
        float mg = 0.f;
        #pragma unroll
        for (int mf = 0; mf < 2; ++mf)
            #pragma unroll
            for (int i = 0; i < 4; ++i) {
                pm[mf][i] *= 0.125f;
                mg = fmaxf(mg, pm[mf][i] - m_run[mf][i]);
            }
        if (__any(mg > 8.0f)) {
            #pragma unroll
            for (int mf = 0; mf < 2; ++mf)
                #pragma unroll
                for (int i = 0; i < 4; ++i) {
                    float mn = fmaxf(m_run[mf][i], pm[mf][i]);
                    float corr = __expf(m_run[mf][i] - mn);
                    m_run[mf][i] = mn;
                    lpp[mf][i] *= corr;
                    #pragma unroll
                    for (int df = 0; df < 4; ++df) o_acc[mf][df][i] *= corr;
                }
        }
        #pragma unroll
        for (int mf = 0; mf < 2; ++mf)
            #pragma unroll
            for (int nf = 0; nf < 4; ++nf)
                #pragma unroll
                for (int i = 0; i < 4; ++i) {
                    float p = __expf(fmaf(s_acc[mf][nf][i], 0.125f, -m_run[mf][i]));
                    P[(mf * 16 + g * 4 + i) * 72 + nf * 16 + c] = f2bu(p);
                    lpp[mf][i] += p;
                }
        #pragma unroll
        for (int ks = 0; ks < 2; ++ks) {
            short8 pa[2];
            #pragma unroll
            for (int mf = 0; mf < 2; ++mf)
                pa[mf] = *(const short8*)(P + (mf * 16 + c) * 72 + ks * 32 + g * 8);
            #pragma unroll
            for (int mf = 0; mf < 2; ++mf)
                #pragma unroll
                for (int df = 0; df < 4; ++df)
                    o_acc[mf][df] = __builtin_amdgcn_mfma_f32_16x16x32_bf16(pa[mf], vf[ks][df], o_acc[mf][df], 0, 0, 0);
        }
    }
    #pragma unroll
    for (int mf = 0; mf < 2; ++mf)
        #pragma unroll
        for (int i = 0; i < 4; ++i)
            lpp[mf][i] = sum16(lpp[mf][i]);
    long pbase = (long)(bh * 160 + item);
    #pragma unroll
    for (int mf = 0; mf < 2; ++mf)
        #pragma unroll
        for (int i = 0; i < 4; ++i) {
            int row_l = mf * 16 + g * 4 + i;
            #pragma unroll
            for (int df = 0; df < 4; ++df)
                opart[pbase * 2048 + row_l * 64 + df * 16 + c] = f2bu(o_acc[mf][df][i]);
            if (c == 0) {
                mpart[pbase * 32 + row_l] = m_run[mf][i];
                lpart[pbase * 32 + row_l] = lpp[mf][i];
            }
        }
}

// ---------------- flash merge: combine <=4 bf16 partials per (bh,strip) -> bf16 y ----------------
__global__ __launch_bounds__(256)
void k_flash_merge(const unsigned short* __restrict__ opart, const float* __restrict__ mpart,
                   const float* __restrict__ lpart, unsigned short* __restrict__ yout) {
    int bs = blockIdx.x;
    int bh = bs >> 6, strip = bs & 63;
    int b = bh >> 4, h = bh & 15;
    int np, base;
    if (strip < 16)      { np = 1; base = strip; }
    else if (strip < 32) { np = 2; base = 16 + (strip - 16) * 2; }
    else if (strip < 48) { np = 3; base = 48 + (strip - 32) * 3; }
    else                 { np = 4; base = 96 + (strip - 48) * 4; }
    long p0 = (long)(bh * 160 + base);
    int tid = threadIdx.x;
    int r = tid >> 3, c0 = (tid & 7) * 8;
    float M = -3.0e38f;
    for (int p = 0; p < np; ++p) M = fmaxf(M, mpart[(p0 + p) * 32 + r]);
    float L = 0.f;
    float acc[8] = {};
    for (int p = 0; p < np; ++p) {
        float sc = __expf(mpart[(p0 + p) * 32 + r] - M);
        L += lpart[(p0 + p) * 32 + r] * sc;
        const unsigned short* op = opart + (p0 + p) * 2048 + r * 64 + c0;
        ushort4 a = *(const ushort4*)op;
        ushort4 bq = *(const ushort4*)(op + 4);
        acc[0] += bu2f(a.x) * sc; acc[1] += bu2f(a.y) * sc;
        acc[2] += bu2f(a.z) * sc; acc[3] += bu2f(a.w) * sc;
        acc[4] += bu2f(bq.x) * sc; acc[5] += bu2f(bq.y) * sc;
        acc[6] += bu2f(bq.z) * sc; acc[7] += bu2f(bq.w) * sc;
    }
    float inv = 1.0f / L;
    long row = (long)b * Tc + strip * 32 + r;
    unsigned short* yp = yout + row * 1024 + h * 64 + c0;
    ushort4 o1, o2;
    o1.x = f2bu(acc[0] * inv); o1.y = f2bu(acc[1] * inv); o1.z = f2bu(acc[2] * inv); o1.w = f2bu(acc[3] * inv);
    o2.x = f2bu(acc[4] * inv); o2.y = f2bu(acc[5] * inv); o2.z = f2bu(acc[6] * inv); o2.w = f2bu(acc[7] * inv);
    *(ushort4*)yp = o1;
    *(ushort4*)(yp + 4) = o2;
}

// ---------------- AFT gated cumsum (bf16 qkv): 3-pass chunked ----------------
__global__ void k_aft_p1(const unsigned short* __restrict__ qkv, float* __restrict__ cw, float* __restrict__ cs) {
    int id = blockIdx.x * TPB + threadIdx.x;
    int bc = id & 2047, ch = id >> 11;
    int b = bc >> 10, c = bc & 1023;
    const unsigned short* base = qkv + ((long)(b * Tc + ch * CHL)) * 3072 + c;
    float sw = 0.f, sv = 0.f;
    for (int i = 0; i < CHL; ++i) {
        float k = bu2f(base[1024]), v = bu2f(base[2048]);
        float e = __expf(k);
        sw += e; sv += e * v;
        base += 3072;
    }
    cw[ch * 2048 + bc] = sw; cs[ch * 2048 + bc] = sv;
}

__global__ void k_aft_p2(float* __restrict__ cw, float* __restrict__ cs) {
    int bc = blockIdx.x * TPB + threadIdx.x;
    float rw = 0.f, rv = 0.f;
    for (int ch = 0; ch < NCH; ++ch) {
        long idx = (long)ch * 2048 + bc;
        float tw = cw[idx], tv = cs[idx];
        cw[idx] = rw; cs[idx] = rv; rw += tw; rv += tv;
    }
}

__global__ void k_aft_p3(const unsigned short* __restrict__ qkv, const float* __restrict__ cw,
                         const float* __restrict__ cs, unsigned short* __restrict__ y) {
    int id = blockIdx.x * TPB + threadIdx.x;
    int bc = id & 2047, ch = id >> 11;
    int b = bc >> 10, c = bc & 1023;
    float aw = cw[ch * 2048 + bc], av = cs[ch * 2048 + bc];
    long t0 = (long)b * Tc + ch * CHL;
    const unsigned short* base = qkv + t0 * 3072 + c;
    unsigned short* yp = y + t0 * 1024 + c;
    for (int i = 0; i < CHL; ++i) {
        float q = bu2f(base[0]), k = bu2f(base[1024]), v = bu2f(base[2048]);
        float e = __expf(k);
        av += e * v; aw += e;
        float sig = 1.0f / (1.0f + __expf(-q));
        yp[0] = f2bu(sig * av / (aw + 1e-6f));
        base += 3072; yp += 1024;
    }
}

// ---------------- fused u*silu(v) -> bf16 + rowrms(u), bf16 uv in (block per row) ----------------
__global__ void k_silu_rms(const unsigned short* __restrict__ uv, unsigned short* __restrict__ g,
                           float* __restrict__ rs) {
    __shared__ float red[TPB];
    long row = blockIdx.x;
    const unsigned short* up = uv + row * 2048;
    ushort4 u4 = *(const ushort4*)(up + threadIdx.x * 4);
    ushort4 v4 = *(const ushort4*)(up + 1024 + threadIdx.x * 4);
    float u0 = bu2f(u4.x), u1 = bu2f(u4.y), u2 = bu2f(u4.z), u3 = bu2f(u4.w);
    float v0 = bu2f(v4.x), v1 = bu2f(v4.y), v2 = bu2f(v4.z), v3 = bu2f(v4.w);
    ushort4 o;
    o.x = f2bu(u0 * v0 / (1.f + __expf(-v0)));
    o.y = f2bu(u1 * v1 / (1.f + __expf(-v1)));
    o.z = f2bu(u2 * v2 / (1.f + __expf(-v2)));
    o.w = f2bu(u3 * v3 / (1.f + __expf(-v3)));
    *(ushort4*)(g + row * 1024 + threadIdx.x * 4) = o;
    red[threadIdx.x] = u0 * u0 + u1 * u1 + u2 * u2 + u3 * u3;
    __syncthreads();
    for (int off = 128; off > 0; off >>= 1) {
        if (threadIdx.x < off) red[threadIdx.x] += red[threadIdx.x + off];
        __syncthreads();
    }
    if (threadIdx.x == 0) rs[row] = rsqrtf(red[0] / 1024.0f + F32_EPS);
}

// ---------------- u * silu(v) -> bf16 (final swiglu, bf16 in) ----------------
__global__ void k_silu_gate(const unsigned short* __restrict__ uv, unsigned short* __restrict__ g, long n4) {
    long i = (long)blockIdx.x * TPB + threadIdx.x;
    if (i >= n4) return;
    long r = i >> 8, c4 = i & 255;
    ushort4 u4 = *(const ushort4*)(uv + r * 2048 + c4 * 4);
    ushort4 v4 = *(const ushort4*)(uv + r * 2048 + 1024 + c4 * 4);
    float u0 = bu2f(u4.x), u1 = bu2f(u4.y), u2 = bu2f(u4.z), u3 = bu2f(u4.w);
    float v0 = bu2f(v4.x), v1 = bu2f(v4.y), v2 = bu2f(v4.z), v3 = bu2f(v4.w);
    ushort4 o;
    o.x = f2bu(u0 * v0 / (1.f + __expf(-v0)));
    o.y = f2bu(u1 * v1 / (1.f + __expf(-v1)));
    o.z = f2bu(u2 * v2 / (1.f + __expf(-v2)));
    o.w = f2bu(u3 * v3 / (1.f + __expf(-v3)));
    *(ushort4*)(g + r * 1024 + c4 * 4) = o;
}

// ---------------- w_out = p*s*silu(w_in) + w_in  (also emits bf16 copy) ----------------
__global__ void k_wupdate(float* __restrict__ wout, const float* __restrict__ win,
                          const float* __restrict__ p, const float* __restrict__ scale,
                          unsigned short* __restrict__ wb, long n4) {
    long i = (long)blockIdx.x * TPB + threadIdx.x;
    if (i >= n4) return;
    float s = scale[0];
    float4 wv = *(const float4*)(win + i * 4);
    float4 pv = *(const float4*)(p + i * 4);
    float4 o;
    o.x = pv.x * s * (wv.x / (1.f + __expf(-wv.x))) + wv.x;
    o.y = pv.y * s * (wv.y / (1.f + __expf(-wv.y))) + wv.y;
    o.z = pv.z * s * (wv.z / (1.f + __expf(-wv.z))) + wv.z;
    o.w = pv.w * s * (wv.w / (1.f + __expf(-wv.w))) + wv.w;
    *(float4*)(wout + i * 4) = o;
    ushort4 ob; ob.x = f2bu(o.x); ob.y = f2bu(o.y); ob.z = f2bu(o.z); ob.w = f2bu(o.w);
    *(ushort4*)(wb + i * 4) = ob;
}

// ---------------- 4-slab reduce + scale + row softmax -> fp32 out ----------------
__global__ void k_softmax4(const float* __restrict__ parts, float* __restrict__ outb, float fscale) {
    __shared__ float red[TPB];
    __shared__ float rowbuf[1024];
    long row = blockIdx.x;
    const float* p0 = parts + row * 1024;
    for (int c = threadIdx.x; c < 1024; c += TPB) {
        float v = p0[c] + p0[c + 1048576] + p0[c + 2097152] + p0[c + 3145728];
        rowbuf[c] = v * fscale;
    }
    __syncthreads();
    float m = -3.0e38f;
    for (int c = threadIdx.x; c < 1024; c += TPB) m = fmaxf(m, rowbuf[c]);
    red[threadIdx.x] = m; __syncthreads();
    for (int o = 128; o > 0; o >>= 1) {
        if (threadIdx.x < o) red[threadIdx.x] = fmaxf(red[threadIdx.x], red[threadIdx.x + o]);
        __syncthreads();
    }
    m = red[0]; __syncthreads();
    float sum = 0.f;
    for (int c = threadIdx.x; c < 1024; c += TPB) sum += __expf(rowbuf[c] - m);
    red[threadIdx.x] = sum; __syncthreads();
    for (int o = 128; o > 0; o >>= 1) {
        if (threadIdx.x < o) red[threadIdx.x] += red[threadIdx.x + o];
        __syncthreads();
    }
    float inv = 1.0f / red[0];
    for (int c = threadIdx.x; c < 1024; c += TPB)
        outb[row * 1024 + c] = __expf(rowbuf[c] - m) * inv;
}

// ---------------- tea: rotary + per-head rmsnorm + split, bf16 in/out ----------------
__global__ void k_rot_split(const unsigned short* __restrict__ qkvp, const float* __restrict__ cosp,
                            const float* __restrict__ sinp, unsigned short* __restrict__ hq,
                            unsigned short* __restrict__ hk, unsigned short* __restrict__ hv) {
    __shared__ float row[3072];
    __shared__ float cs[32], sn[32];
    int bt = blockIdx.x;
    int b = bt >> 11, t = bt & 2047;
    const unsigned short* src = qkvp + (long)bt * 3072;
    #pragma unroll
    for (int u = 0; u < 3; ++u) {
        int idx = threadIdx.x + u * 256;
        ushort4 v = *(const ushort4*)(src + idx * 4);
        row[idx * 4 + 0] = bu2f(v.x); row[idx * 4 + 1] = bu2f(v.y);
        row[idx * 4 + 2] = bu2f(v.z); row[idx * 4 + 3] = bu2f(v.w);
    }
    if (threadIdx.x < 32) { cs[threadIdx.x] = cosp[t * 32 + threadIdx.x]; sn[threadIdx.x] = sinp[t * 32 + threadIdx.x]; }
    __syncthreads();
    int h = threadIdx.x >> 4, li = threadIdx.x & 15;
    int base = h * 192;
    long obase = ((long)(b * Hc + h) * Tc + t) * 64 + li * 4;
    {
        float r[4]; float ss = 0.f;
        #pragma unroll
        for (int j = 0; j < 4; ++j) {
            int d = li * 4 + j;
            float val = (d < 32) ? (row[base + d] * cs[d] + row[base + d + 32] * sn[d])
                                 : (-row[base + d - 32] * sn[d - 32] + row[base + d] * cs[d - 32]);
            r[j] = val; ss += val * val;
        }
        ss = sum16(ss);
        float sc = rsqrtf(ss / 64.0f + F32_EPS);
        ushort4 o; o.x = f2bu(r[0] * sc); o.y = f2bu(r[1] * sc); o.z = f2bu(r[2] * sc); o.w = f2bu(r[3] * sc);
        *(ushort4*)(hq + obase) = o;
    }
    {
        int kb = base + 64;
        float r[4]; float ss = 0.f;
        #pragma unroll
        for (int j = 0; j < 4; ++j) {
            int d = li * 4 + j;
            float val = (d < 32) ? (row[kb + d] * cs[d] + row[kb + d + 32] * sn[d])
                                 : (-row[kb + d - 32] * sn[d - 32] + row[kb + d] * cs[d - 32]);
            r[j] = val; ss += val * val;
        }
        ss = sum16(ss);
        float sc = rsqrtf(ss / 64.0f + F32_EPS);
        ushort4 o; o.x = f2bu(r[0] * sc); o.y = f2bu(r[1] * sc); o.z = f2bu(r[2] * sc); o.w = f2bu(r[3] * sc);
        *(ushort4*)(hk + obase) = o;
    }
    {
        ushort4 o;
        o.x = f2bu(row[base + 128 + li * 4 + 0]); o.y = f2bu(row[base + 128 + li * 4 + 1]);
        o.z = f2bu(row[base + 128 + li * 4 + 2]); o.w = f2bu(row[base + 128 + li * 4 + 3]);
        *(ushort4*)(hv + obase) = o;
    }
}

extern "C" void kernel_launch(void* const* d_in, const int* in_sizes, int n_in,
                              void* d_out, int out_size, void* d_ws, size_t ws_size,
                              hipStream_t stream) {
    const float* x_in = (const float*)d_in[0];
    const float* w_in = (const float*)d_in[1];
    const float* cos_in = (const float*)d_in[2];
    const float* sin_in = (const float*)d_in[3];
    float* out = (float*)d_out;
    float* ws = (float*)d_ws;

    long off = 0;
    float* w_cur = ws + off;  off += (long)WR * Ec;
    float* w_tmp = ws + off;  off += (long)WR * Ec;   // also: oa split-K partials (4M floats)
    float* xbuf  = ws + off;  off += BT * Ec;
    float* R     = ws + off;  off += BT * 3L * QKVc;  // bf16 qkvb+uvb | bf16 opart | split-K slabs
    float* oab   = ws + off;  off += (long)Ec * Ec;   // also: flash m/l partials
    float* red   = ws + off;  off += 16384;
    float* scales= ws + off;  off += 16;
    float* uscale= ws + off;  off += 4096;
    float* chw   = ws + off;  off += 2048L * NCH;
    float* chs   = ws + off;  off += 2048L * NCH;
    unsigned short* qkvb  = (unsigned short*)R;          // 12.58M ushorts
    unsigned short* uvb   = qkvb + 12582912L;            // 8.39M ushorts
    unsigned short* opartb= qkvb;                         // final-phase alias
    unsigned short* wsplit = qkvb;                        // w@oa split slabs (2 x 6.29M)
    unsigned short* osplit = uvb;                         // out-proj split slabs (2 x 4.19M)
    float* mpart = oab;
    float* lpart = oab + 5120L * 32;

    unsigned short* bp = (unsigned short*)(ws + off);
    long bo = 0;
    unsigned short* wb  = bp + bo; bo += (long)WR * Ec;
    unsigned short* xbn = bp + bo; bo += BT * Ec;
    unsigned short* ybn = bp + bo; bo += BT * Ec;
    unsigned short* gbn = bp + bo; bo += BT * Ec;
    unsigned short* t1  = bp + bo; bo += BT * Ec;            // o^T | hq
    unsigned short* t2  = bp + bo; bo += BT * Ec;            // v^T | hk
    unsigned short* t3  = bp + bo; bo += BT * Ec;            // oa^T | hvS
    unsigned short* t4  = bp + bo; bo += BT * Ec;            // hvT

    const float rsWR = 1.0f / sqrtf(6144.0f);
    const long wsw = 3072L * 1024, wout = 5120L * 1024;

    // one-time bf16 copy of w (from input)
    k_cast_bf16<<<(int)(((long)WR * Ec / 4) / TPB), TPB, 0, stream>>>(w_in, wb, (long)WR * Ec / 4);
    // layer 0's rmsnorm of x_in (later layers get xbn from the fused merge)
    k_rms1024b<<<BT, TPB, 0, stream>>>(x_in, xbn, 1024, 1024);

    for (int layer = 0; layer < 2; ++layer) {
        const float* wsrc = layer == 0 ? w_in : w_cur;   // fp32 weights
        const float* xsrc = layer == 0 ? x_in : xbuf;    // fp32 activations (residual)
        k_std_partial3<<<dim3(256, 3), TPB, 0, stream>>>(wsrc, red);
        k_std_final3<<<1, TPB, 0, stream>>>(red, scales);
        k_bgemm<1><<<dim3(24, 32, 1), TPB, 0, stream>>>(
            1024, xbn, 1024, 0, wb, 1024, 0, qkvb, 3072, 0, 0, 1, scales + 0, 1.0f, nullptr, 0);
        k_rms_qk<<<8192, TPB, 0, stream>>>(qkvb);
        k_aft_p1<<<(2048 * NCH) / TPB, TPB, 0, stream>>>(qkvb, chw, chs);
        k_aft_p2<<<2048 / TPB, TPB, 0, stream>>>(chw, chs);
        k_aft_p3<<<(2048 * NCH) / TPB, TPB, 0, stream>>>(qkvb, chw, chs, ybn);
        k_bgemm<1><<<dim3(16, 32, 1), TPB, 0, stream>>>(
            1024, ybn, 1024, 0, wb + wsw, 1024, 0, uvb, 2048, 0, 0, 1, scales + 1, 1.0f, nullptr, 0);
        k_silu_rms<<<BT, TPB, 0, stream>>>(uvb, gbn, uscale);
        k_tcast2<<<dim3(16, 64, 2), TPB, 0, stream>>>(uvb, uscale, t1, t2);
        // oa = softmax(o^T @ a * E^-0.5), split-K x4 into w_tmp partials
        k_bgemm<0><<<dim3(8, 8, 4), TPB, 0, stream>>>(
            1024, t1, 4096, 0, t2, 4096, 0, w_tmp, 1024, 0, 1048576L, 4, nullptr, 1.0f, nullptr, 0);
        k_softmax4<<<1024, TPB, 0, stream>>>(w_tmp, oab, 0.03125f);
        k_tcast<float><<<dim3(16, 16, 1), TPB, 0, stream>>>(oab, 1024, 0, t3, 1024, 0, nullptr);
        // x' = x + g @ w_out^T * s2 : split-K x2 + fused merge+residual+rmsnorm
        k_bgemm<1><<<dim3(8, 32, 2), TPB, 0, stream>>>(
            512, gbn, 1024, 0, wb + wout, 1024, 0, osplit, 1024, 0, 4194304L, 2, scales + 2, 1.0f, nullptr, 0);
        k_merge2rms<<<BT, TPB, 0, stream>>>(osplit, osplit + 4194304L, xsrc, xbuf, xbn);
        // w_tmp = w @ oa : split-K x2 + fused merge+stats
        k_bgemm<1><<<dim3(8, 48, 2), TPB, 0, stream>>>(
            512, wb, 1024, 0, t3, 1024, 0, wsplit, 1024, 0, 6291456L, 2, nullptr, 1.0f, nullptr, 0);
        k_merge2stat<<<(int)(((long)WR * 1024 / 4) / TPB), TPB, 0, stream>>>(
            wsplit, wsplit + 6291456L, w_tmp, red);
        k_std_finalB<<<1, TPB, 0, stream>>>(red, (float)((long)WR * 1024), rsWR, scales + 3);
        k_wupdate<<<(int)(((long)WR * 1024 / 4) / TPB), TPB, 0, stream>>>(
            w_cur, wsrc, w_tmp, scales + 3, wb, (long)WR * 1024 / 4);
    }

    // -------- final tea (no w_norm); xbn already holds rmsnorm(x) from layer 1's merge --------
    k_bgemm<1><<<dim3(24, 32, 1), TPB, 0, stream>>>(
        1024, xbn, 1024, 0, wb, 1024, 0, qkvb, 3072, 0, 0, 1, nullptr, 1.0f, nullptr, 0);
    k_rot_split<<<BT, TPB, 0, stream>>>(qkvb, cos_in, sin_in, t1, t2, t3);
    k_tcast<unsigned short><<<dim3(1, 32, 32), TPB, 0, stream>>>(
        t3, 64, (long)Tc * 64, t4, 2048, (long)Tc * 64, nullptr);
    // flash-decoding: 5120 items in 1280 blocks (4 waves/block, independent), then merge
    k_flash_split<<<dim3(1280), TPB, 0, stream>>>(t1, t2, t4, opartb, mpart, lpart);
    k_flash_merge<<<dim3(2048), TPB, 0, stream>>>(opartb, mpart, lpart, ybn);
    // final swiglu -> d_out
    k_bgemm<1><<<dim3(16, 32, 1), TPB, 0, stream>>>(
        1024, ybn, 1024, 0, wb + wsw, 1024, 0, uvb, 2048, 0, 0, 1, nullptr, 1.0f, nullptr, 0);
    k_silu_gate<<<(int)((BT * 1024 / 4) / TPB), TPB, 0, stream>>>(uvb, gbn, BT * 1024 / 4);
    // final out-proj: split-K x2 into dead qkvb region + merge(+x residual) -> out
    k_bgemm<1><<<dim3(8, 32, 2), TPB, 0, stream>>>(
        512, gbn, 1024, 0, wb + wout, 1024, 0, qkvb, 1024, 0, 4194304L, 2, nullptr, 1.0f, nullptr, 0);
    k_merge2<<<(int)((BT * 1024 / 4) / TPB), TPB, 0, stream>>>(
        qkvb, qkvb + 4194304L, xbuf, out, BT * 1024 / 4);
}

// Round 15
// 712.883 us; speedup vs baseline: 1.2134x; 1.0302x over previous
//
#include <hip/hip_runtime.h>
#include <hip/hip_bf16.h>
#include <math.h>

#define TPB 256

constexpr int Bc = 2, Tc = 2048, Ec = 1024, QKVc = 1024, Hc = 16, DHc = 64;
constexpr long BT = (long)Bc * Tc;     // 4096
constexpr int WR = 5 * QKVc + Ec;      // 6144
constexpr float F32_EPS = 1.1920928955078125e-07f;
constexpr int NCH = 64, CHL = Tc / NCH;

typedef __attribute__((ext_vector_type(8))) short short8;
typedef __attribute__((ext_vector_type(4))) float f32x4;

__device__ __forceinline__ unsigned short f2bu(float f) {
    union { __hip_bfloat16 h; unsigned short u; } c; c.h = __float2bfloat16(f); return c.u;
}
__device__ __forceinline__ float bu2f(unsigned short u) {
    union { __hip_bfloat16 h; unsigned short u; } c; c.u = u; return __bfloat162float(c.h);
}
__device__ __forceinline__ float ldval(const float* p) { return *p; }
__device__ __forceinline__ float ldval(const unsigned short* p) { return bu2f(*p); }

__device__ __forceinline__ void gload_lds16(const void* g, void* l) {
    __builtin_amdgcn_global_load_lds((const __attribute__((address_space(1))) void*)g,
                                     (__attribute__((address_space(3))) void*)l, 16, 0, 0);
}

// ---- DPP cross-lane (VALU pipe): reduce over 16-lane groups ----
template<int CTRL>
__device__ __forceinline__ float dppf(float x) {
    union { float f; int i; } a, b;
    a.f = x;
    b.i = __builtin_amdgcn_update_dpp(0, a.i, CTRL, 0xF, 0xF, true);
    return b.f;
}
__device__ __forceinline__ float max16(float v) {
    v = fmaxf(v, dppf<0xB1>(v));
    v = fmaxf(v, dppf<0x4E>(v));
    v = fmaxf(v, dppf<0x124>(v));
    v = fmaxf(v, dppf<0x128>(v));
    return v;
}
__device__ __forceinline__ float sum16(float v) {
    v += dppf<0xB1>(v);
    v += dppf<0x4E>(v);
    v += dppf<0x124>(v);
    v += dppf<0x128>(v);
    return v;
}

// ---------------- fused 3-segment global std (ddof=1) for w_qkv/w_sw/w_out ----------------
__global__ void k_std_partial3(const float* __restrict__ w, float* __restrict__ out) {
    __shared__ float ls[TPB], lss[TPB];
    int seg = blockIdx.y;
    long base = (seg == 0) ? 0L : (seg == 1 ? 3072L * 1024 : 5120L * 1024);
    long n    = (seg == 0) ? 3072L * 1024 : (seg == 1 ? 2048L * 1024 : 1024L * 1024);
    const float* p = w + base;
    float s = 0.f, ss = 0.f;
    for (long i = (long)blockIdx.x * TPB + threadIdx.x; i < n; i += 256L * TPB) {
        float v = p[i]; s += v; ss += v * v;
    }
    ls[threadIdx.x] = s; lss[threadIdx.x] = ss; __syncthreads();
    for (int o = 128; o > 0; o >>= 1) {
        if (threadIdx.x < o) { ls[threadIdx.x] += ls[threadIdx.x + o]; lss[threadIdx.x] += lss[threadIdx.x + o]; }
        __syncthreads();
    }
    if (threadIdx.x == 0) { out[seg * 512 + blockIdx.x] = ls[0]; out[seg * 512 + 256 + blockIdx.x] = lss[0]; }
}

__global__ void k_std_final3(const float* __restrict__ part, float* __restrict__ scales) {
    __shared__ float ls[TPB], lss[TPB];
    for (int seg = 0; seg < 3; ++seg) {
        ls[threadIdx.x] = part[seg * 512 + threadIdx.x];
        lss[threadIdx.x] = part[seg * 512 + 256 + threadIdx.x];
        __syncthreads();
        for (int o = 128; o > 0; o >>= 1) {
            if (threadIdx.x < o) { ls[threadIdx.x] += ls[threadIdx.x + o]; lss[threadIdx.x] += lss[threadIdx.x + o]; }
            __syncthreads();
        }
        if (threadIdx.x == 0) {
            float n = (seg == 0) ? 3145728.0f : (seg == 1 ? 2097152.0f : 1048576.0f);
            float var = (lss[0] - ls[0] * ls[0] / n) / (n - 1.0f);
            scales[seg] = 0.03125f / (sqrtf(fmaxf(var, 0.0f)) + 1e-8f);
        }
        __syncthreads();
    }
}

// ---------------- big std final: reduce 6144 per-block partials -> scale ----------------
__global__ void k_std_finalB(const float* __restrict__ red, float n, float rs, float* __restrict__ scale) {
    __shared__ float ls[TPB], lss[TPB];
    float s = 0.f, ss = 0.f;
    for (int i = threadIdx.x; i < 6144; i += TPB) { s += red[i]; ss += red[8192 + i]; }
    ls[threadIdx.x] = s; lss[threadIdx.x] = ss; __syncthreads();
    for (int o = 128; o > 0; o >>= 1) {
        if (threadIdx.x < o) { ls[threadIdx.x] += ls[threadIdx.x + o]; lss[threadIdx.x] += lss[threadIdx.x + o]; }
        __syncthreads();
    }
    if (threadIdx.x == 0) {
        float var = (lss[0] - ls[0] * ls[0] / n) / (n - 1.0f);
        scale[0] = rs / (sqrtf(fmaxf(var, 0.0f)) + 1e-8f);
    }
}

// ---------------- in-place rmsnorm of q and k halves of bf16 qkv (grid 8192) ----------------
__global__ void k_rms_qk(unsigned short* __restrict__ qkv) {
    __shared__ float red[TPB];
    int bid = blockIdx.x;
    long row = bid >> 1; int half = bid & 1;
    unsigned short* p = qkv + row * 3072 + half * 1024;
    ushort4 v = *(const ushort4*)(p + threadIdx.x * 4);
    float f0 = bu2f(v.x), f1 = bu2f(v.y), f2 = bu2f(v.z), f3 = bu2f(v.w);
    red[threadIdx.x] = f0 * f0 + f1 * f1 + f2 * f2 + f3 * f3;
    __syncthreads();
    for (int o = 128; o > 0; o >>= 1) {
        if (threadIdx.x < o) red[threadIdx.x] += red[threadIdx.x + o];
        __syncthreads();
    }
    float sc = rsqrtf(red[0] / 1024.0f + F32_EPS);
    ushort4 o4; o4.x = f2bu(f0 * sc); o4.y = f2bu(f1 * sc); o4.z = f2bu(f2 * sc); o4.w = f2bu(f3 * sc);
    *(ushort4*)(p + threadIdx.x * 4) = o4;
}

// ---------------- rmsnorm over 1024 cols, fp32 in -> bf16 out (layer 0 only) ----------------
__global__ void k_rms1024b(const float* __restrict__ in, unsigned short* __restrict__ out, long ldin, long ldout) {
    __shared__ float red[TPB];
    long row = blockIdx.x;
    float4 v = *(const float4*)(in + row * ldin + threadIdx.x * 4);
    float ss = v.x * v.x + v.y * v.y + v.z * v.z + v.w * v.w;
    red[threadIdx.x] = ss; __syncthreads();
    for (int o = 128; o > 0; o >>= 1) {
        if (threadIdx.x < o) red[threadIdx.x] += red[threadIdx.x + o];
        __syncthreads();
    }
    float sc = rsqrtf(red[0] / 1024.0f + F32_EPS);
    ushort4 o4; o4.x = f2bu(v.x * sc); o4.y = f2bu(v.y * sc); o4.z = f2bu(v.z * sc); o4.w = f2bu(v.w * sc);
    *(ushort4*)(out + row * ldout + threadIdx.x * 4) = o4;
}

// ---------------- fp32 -> bf16 cast ----------------
__global__ void k_cast_bf16(const float* __restrict__ in, unsigned short* __restrict__ out, long n4) {
    long i = (long)blockIdx.x * TPB + threadIdx.x;
    if (i >= n4) return;
    float4 v = *(const float4*)(in + i * 4);
    ushort4 o; o.x = f2bu(v.x); o.y = f2bu(v.y); o.z = f2bu(v.z); o.w = f2bu(v.w);
    *(ushort4*)(out + i * 4) = o;
}

// ---------------- merge 2 bf16 split-K slabs -> fp32 (+opt residual) ----------------
__global__ void k_merge2(const unsigned short* __restrict__ p0, const unsigned short* __restrict__ p1,
                         const float* __restrict__ resid, float* __restrict__ outp, long n4) {
    long i = (long)blockIdx.x * TPB + threadIdx.x;
    if (i >= n4) return;
    ushort4 a = *(const ushort4*)(p0 + i * 4);
    ushort4 b = *(const ushort4*)(p1 + i * 4);
    float4 o;
    o.x = bu2f(a.x) + bu2f(b.x); o.y = bu2f(a.y) + bu2f(b.y);
    o.z = bu2f(a.z) + bu2f(b.z); o.w = bu2f(a.w) + bu2f(b.w);
    if (resid) {
        float4 r = *(const float4*)(resid + i * 4);
        o.x += r.x; o.y += r.y; o.z += r.z; o.w += r.w;
    }
    *(float4*)(outp + i * 4) = o;
}

// ---------------- merge 2 slabs + residual + rmsnorm: writes fp32 x and bf16 rms(x) ----------------
__global__ void k_merge2rms(const unsigned short* __restrict__ p0, const unsigned short* __restrict__ p1,
                            const float* __restrict__ resid, float* __restrict__ xout,
                            unsigned short* __restrict__ xbn) {
    __shared__ float red[TPB];
    long row = blockIdx.x;
    long i = row * 256 + threadIdx.x;
    ushort4 a = *(const ushort4*)(p0 + i * 4);
    ushort4 b = *(const ushort4*)(p1 + i * 4);
    float4 r = *(const float4*)(resid + i * 4);
    float4 o;
    o.x = bu2f(a.x) + bu2f(b.x) + r.x; o.y = bu2f(a.y) + bu2f(b.y) + r.y;
    o.z = bu2f(a.z) + bu2f(b.z) + r.z; o.w = bu2f(a.w) + bu2f(b.w) + r.w;
    *(float4*)(xout + i * 4) = o;
    red[threadIdx.x] = o.x * o.x + o.y * o.y + o.z * o.z + o.w * o.w;
    __syncthreads();
    for (int off = 128; off > 0; off >>= 1) {
        if (threadIdx.x < off) red[threadIdx.x] += red[threadIdx.x + off];
        __syncthreads();
    }
    float sc = rsqrtf(red[0] / 1024.0f + F32_EPS);
    ushort4 ob; ob.x = f2bu(o.x * sc); ob.y = f2bu(o.y * sc); ob.z = f2bu(o.z * sc); ob.w = f2bu(o.w * sc);
    *(ushort4*)(xbn + i * 4) = ob;
}

// ---------------- stats of (slab0+slab1) without materializing the sum ----------------
__global__ void k_stat2(const unsigned short* __restrict__ p0, const unsigned short* __restrict__ p1,
                        float* __restrict__ red) {
    __shared__ float ls[TPB], lss[TPB];
    long i = (long)blockIdx.x * TPB + threadIdx.x;
    ushort4 a = *(const ushort4*)(p0 + i * 4);
    ushort4 b = *(const ushort4*)(p1 + i * 4);
    float o0 = bu2f(a.x) + bu2f(b.x), o1 = bu2f(a.y) + bu2f(b.y);
    float o2 = bu2f(a.z) + bu2f(b.z), o3 = bu2f(a.w) + bu2f(b.w);
    ls[threadIdx.x] = o0 + o1 + o2 + o3;
    lss[threadIdx.x] = o0 * o0 + o1 * o1 + o2 * o2 + o3 * o3;
    __syncthreads();
    for (int off = 128; off > 0; off >>= 1) {
        if (threadIdx.x < off) { ls[threadIdx.x] += ls[threadIdx.x + off]; lss[threadIdx.x] += lss[threadIdx.x + off]; }
        __syncthreads();
    }
    if (threadIdx.x == 0) { red[blockIdx.x] = ls[0]; red[8192 + blockIdx.x] = lss[0]; }
}

// ---------------- transpose-cast: in[R][C] (ld, opt rowscale) -> bf16 out[C][R] ----------------
template<typename TI>
__global__ void k_tcast(const TI* __restrict__ in, long ldi, long sIn,
                        unsigned short* __restrict__ out, long ldo, long sOut,
                        const float* __restrict__ rowscale) {
    __shared__ float tile[64][65];
    const TI* ip = in + (long)blockIdx.z * sIn;
    unsigned short* op = out + (long)blockIdx.z * sOut;
    int r0 = blockIdx.y * 64, c0 = blockIdx.x * 64;
    int tid = threadIdx.x;
    int rr = tid >> 4, cc = (tid & 15) * 4;
    #pragma unroll
    for (int u = 0; u < 4; ++u) {
        int r = rr + u * 16;
        float sc = rowscale ? rowscale[r0 + r] : 1.0f;
        #pragma unroll
        for (int j = 0; j < 4; ++j)
            tile[r][cc + j] = ldval(ip + (long)(r0 + r) * ldi + c0 + cc + j) * sc;
    }
    __syncthreads();
    #pragma unroll
    for (int u = 0; u < 4; ++u) {
        int c = rr + u * 16;
        ushort4 o;
        o.x = f2bu(tile[cc + 0][c]); o.y = f2bu(tile[cc + 1][c]);
        o.z = f2bu(tile[cc + 2][c]); o.w = f2bu(tile[cc + 3][c]);
        *(ushort4*)(op + (long)(c0 + c) * ldo + r0 + cc) = o;
    }
}

// ---------------- fused transpose of o (rowscaled) and a from packed bf16 uv ----------------
__global__ void k_tcast2(const unsigned short* __restrict__ uv, const float* __restrict__ uscale,
                         unsigned short* __restrict__ t1, unsigned short* __restrict__ t2) {
    __shared__ float tile[64][65];
    int z = blockIdx.z;
    const unsigned short* ip = uv + (z ? 1024 : 0);
    unsigned short* op = z ? t2 : t1;
    int r0 = blockIdx.y * 64, c0 = blockIdx.x * 64;
    int tid = threadIdx.x;
    int rr = tid >> 4, cc = (tid & 15) * 4;
    #pragma unroll
    for (int u = 0; u < 4; ++u) {
        int r = rr + u * 16;
        float sc = z ? 1.0f : uscale[r0 + r];
        ushort4 v = *(const ushort4*)(ip + (long)(r0 + r) * 2048 + c0 + cc);
        tile[r][cc + 0] = bu2f(v.x) * sc; tile[r][cc + 1] = bu2f(v.y) * sc;
        tile[r][cc + 2] = bu2f(v.z) * sc; tile[r][cc + 3] = bu2f(v.w) * sc;
    }
    __syncthreads();
    #pragma unroll
    for (int u = 0; u < 4; ++u) {
        int c = rr + u * 16;
        ushort4 o;
        o.x = f2bu(tile[cc + 0][c]); o.y = f2bu(tile[cc + 1][c]);
        o.z = f2bu(tile[cc + 2][c]); o.w = f2bu(tile[cc + 3][c]);
        *(ushort4*)(op + (long)(c0 + c) * 4096 + r0 + cc) = o;
    }
}

// ---------------- bf16 MFMA GEMM, NT, 128x128 tile, BK=64 ----------------
template<int WRITE_BF16>
__global__ __launch_bounds__(256)
void k_bgemm(int K,
             const unsigned short* __restrict__ A, int lda, long sA,
             const unsigned short* __restrict__ B, int ldb, long sB,
             void* __restrict__ C, int ldc, long sCi, long sSplit, int nsplit,
             const float* __restrict__ scale_ptr, float fscale,
             const float* __restrict__ addp, int ldadd) {
    __shared__ unsigned short Asl[128 * 64];
    __shared__ unsigned short Bsl[128 * 64];
    int bz = blockIdx.z;
    int batch = bz, sp = 0;
    if (nsplit > 1) { batch = bz / nsplit; sp = bz - batch * nsplit; }
    int m0 = blockIdx.y * 128, n0 = blockIdx.x * 128;
    const unsigned short* Ap = A + (long)batch * sA + (long)sp * K;
    const unsigned short* Bp = B + (long)batch * sB + (long)sp * K;
    int tid = threadIdx.x, lane = tid & 63, wave = tid >> 6;
    int wr = wave >> 1, wc = wave & 1;
    f32x4 acc[4][4] = {};
    for (int k0 = 0; k0 < K; k0 += 64) {
        #pragma unroll
        for (int cc = 0; cc < 4; ++cc) {
            int bu = (wave * 4 + cc) * 64;
            int uidx = bu + lane;
            int r = uidx >> 3, slot = uidx & 7;
            int gu = slot ^ (r & 7);
            gload_lds16(Ap + (long)(m0 + r) * lda + k0 + gu * 8, Asl + bu * 8);
        }
        #pragma unroll
        for (int cc = 0; cc < 4; ++cc) {
            int bu = (wave * 4 + cc) * 64;
            int uidx = bu + lane;
            int r = uidx >> 3, slot = uidx & 7;
            int gu = slot ^ (r & 7);
            gload_lds16(Bp + (long)(n0 + r) * ldb + k0 + gu * 8, Bsl + bu * 8);
        }
        __syncthreads();
        #pragma unroll
        for (int ksub = 0; ksub < 2; ++ksub) {
            short8 av[4], bv[4];
            #pragma unroll
            for (int m = 0; m < 4; ++m) {
                int r = wr * 64 + m * 16 + (lane & 15);
                int slot = (ksub * 4 + (lane >> 4)) ^ (r & 7);
                av[m] = *(const short8*)(Asl + r * 64 + slot * 8);
            }
            #pragma unroll
            for (int n = 0; n < 4; ++n) {
                int r = wc * 64 + n * 16 + (lane & 15);
                int slot = (ksub * 4 + (lane >> 4)) ^ (r & 7);
                bv[n] = *(const short8*)(Bsl + r * 64 + slot * 8);
            }
            #pragma unroll
            for (int m = 0; m < 4; ++m)
                #pragma unroll
                for (int n = 0; n < 4; ++n)
                    acc[m][n] = __builtin_amdgcn_mfma_f32_16x16x32_bf16(av[m], bv[n], acc[m][n], 0, 0, 0);
        }
        __syncthreads();
    }
    float s = fscale * (scale_ptr ? scale_ptr[0] : 1.0f);
    long cbase = (long)batch * sCi + (long)sp * sSplit;
    int row0 = m0 + wr * 64, col0 = n0 + wc * 64 + (lane & 15);
    int rbase = (lane >> 4) * 4;
    #pragma unroll
    for (int m = 0; m < 4; ++m)
        #pragma unroll
        for (int i = 0; i < 4; ++i) {
            long row = row0 + m * 16 + rbase + i;
            #pragma unroll
            for (int n = 0; n < 4; ++n) {
                long col = col0 + n * 16;
                float v = acc[m][n][i] * s;
                if (addp) v += addp[row * (long)ldadd + col];
                long idx = cbase + row * ldc + col;
                if (WRITE_BF16) ((unsigned short*)C)[idx] = f2bu(v);
                else ((float*)C)[idx] = v;
            }
        }
}

// ---------------- flash-decoding split: KVBLK=64, DPP softmax ----------------
__global__ __launch_bounds__(256)
void k_flash_split(const unsigned short* __restrict__ hq, const unsigned short* __restrict__ hk,
                   const unsigned short* __restrict__ hvT,
                   unsigned short* __restrict__ opart, float* __restrict__ mpart, float* __restrict__ lpart) {
    __shared__ unsigned short P_lds[4][32 * 72];
    int lane = threadIdx.x & 63, wave = threadIdx.x >> 6;
    unsigned short* P = P_lds[wave];
    int g = lane >> 4, c = lane & 15;
    unsigned bid = blockIdx.x;
    unsigned bswz = (bid & 7) * 160 + (bid >> 3);
    unsigned gi = bswz * 4 + wave;
    unsigned bh = gi / 160, itr = gi % 160;
    int item = 159 - (int)itr;
    int strip, chunk;
    if (item < 16)      { strip = item;                 chunk = 0; }
    else if (item < 48) { strip = 16 + (item - 16) / 2; chunk = (item - 16) & 1; }
    else if (item < 96) { strip = 32 + (item - 48) / 3; chunk = (item - 48) % 3; }
    else                { strip = 48 + (item - 96) / 4; chunk = (item - 96) & 3; }
    int q0 = strip * 32;
    int nt = (q0 + 32 + 63) >> 6;
    int ti0 = chunk * 8;
    int ti1 = ti0 + 8 < nt ? ti0 + 8 : nt;
    const unsigned short* qb = hq + (long)bh * Tc * 64;
    const unsigned short* kb = hk + (long)bh * Tc * 64;
    const unsigned short* vtb = hvT + (long)bh * 64 * Tc;

    short8 qf[2][2];
    #pragma unroll
    for (int mf = 0; mf < 2; ++mf)
        #pragma unroll
        for (int ks = 0; ks < 2; ++ks)
            qf[mf][ks] = *(const short8*)(qb + (long)(q0 + mf * 16 + c) * 64 + ks * 32 + g * 8);

    f32x4 o_acc[2][4] = {};
    float m_run[2][4], lpp[2][4];
    #pragma unroll
    for (int mf = 0; mf < 2; ++mf)
        #pragma unroll
        for (int i = 0; i < 4; ++i) { m_run[mf][i] = -3.0e38f; lpp[mf][i] = 0.f; }

    for (int ti = ti0; ti < ti1; ++ti) {
        int kt = ti * 64;
        short8 vf[2][4];
        #pragma unroll
        for (int ks = 0; ks < 2; ++ks)
            #pragma unroll
            for (int df = 0; df < 4; ++df)
                vf[ks][df] = *(const short8*)(vtb + (long)(df * 16 + c) * Tc + kt + ks * 32 + g * 8);
        f32x4 s_acc[2][4] = {};
        #pragma unroll
        for (int ks = 0; ks < 2; ++ks) {
            short8 kf[4];
            #pragma unroll
            for (int nf = 0; nf < 4; ++nf)
                kf[nf] = *(const short8*)(kb + (long)(kt + nf * 16 + c) * 64 + ks * 32 + g * 8);
            #pragma unroll
            for (int mf = 0; mf < 2; ++mf)
                #pragma unroll
                for (int nf = 0; nf < 4; ++nf)
                    s_acc[mf][nf] = __builtin_amdgcn_mfma_f32_16x16x32_bf16(qf[mf][ks], kf[nf], s_acc[mf][nf], 0, 0, 0);
        }
        if (ti == nt - 1) {
            #pragma unroll
            for (int mf = 0; mf < 2; ++mf)
                #pragma unroll
                for (int nf = 0; nf < 4; ++nf)
                    #pragma unroll
                    for (int i = 0; i < 4; ++i)
                        if ((kt + nf * 16 + c) > (q0 + mf * 16 + g * 4 + i)) s_acc[mf][nf][i] = -1.0e30f;
        }
        float pm[2][4];
        #pragma unroll
        for (int mf = 0; mf < 2; ++mf)
            #pragma unroll
            for (int i = 0; i < 4; ++i)
                pm[mf][i] = max16(fmaxf(fmaxf(s_acc[mf][0][i], s_acc[mf][1][i]),
                                        fmaxf(s_acc[mf][2][i], s_acc[mf][3][i])));
        float mg = 0.f;
        #pragma unroll
        for (int mf = 0; mf < 2; ++mf)
            #pragma unroll
            for (int i = 0; i < 4; ++i) {
                pm[mf][i] *= 0.125f;
                mg = fmaxf(mg, pm[mf][i] - m_run[mf][i]);
            }
        if (__any(mg > 8.0f)) {
            #pragma unroll
            for (int mf = 0; mf < 2; ++mf)
                #pragma unroll
                for (int i = 0; i < 4; ++i) {
                    float mn = fmaxf(m_run[mf][i], pm[mf][i]);
                    float corr = __expf(m_run[mf][i] - mn);
                    m_run[mf][i] = mn;
                    lpp[mf][i] *= corr;
                    #pragma unroll
                    for (int df = 0; df < 4; ++df) o_acc[mf][df][i] *= corr;
                }
        }
        #pragma unroll
        for (int mf = 0; mf < 2; ++mf)
            #pragma unroll
            for (int nf = 0; nf < 4; ++nf)
                #pragma unroll
                for (int i = 0; i < 4; ++i) {
                    float p = __expf(fmaf(s_acc[mf][nf][i], 0.125f, -m_run[mf][i]));
                    P[(mf * 16 + g * 4 + i) * 72 + nf * 16 + c] = f2bu(p);
                    lpp[mf][i] += p;
                }
        #pragma unroll
        for (int ks = 0; ks < 2; ++ks) {
            short8 pa[2];
            #pragma unroll
            for (int mf = 0; mf < 2; ++mf)
                pa[mf] = *(const short8*)(P + (mf * 16 + c) * 72 + ks * 32 + g * 8);
            #pragma unroll
            for (int mf = 0; mf < 2; ++mf)
                #pragma unroll
                for (int df = 0; df < 4; ++df)
                    o_acc[mf][df] = __builtin_amdgcn_mfma_f32_16x16x32_bf16(pa[mf], vf[ks][df], o_acc[mf][df], 0, 0, 0);
        }
    }
    #pragma unroll
    for (int mf = 0; mf < 2; ++mf)
        #pragma unroll
        for (int i = 0; i < 4; ++i)
            lpp[mf][i] = sum16(lpp[mf][i]);
    long pbase = (long)(bh * 160 + item);
    #pragma unroll
    for (int mf = 0; mf < 2; ++mf)
        #pragma unroll
        for (int i = 0; i < 4; ++i) {
            int row_l = mf * 16 + g * 4 + i;
            #pragma unroll
            for (int df = 0; df < 4; ++df)
                opart[pbase * 2048 + row_l * 64 + df * 16 + c] = f2bu(o_acc[mf][df][i]);
            if (c == 0) {
                mpart[pbase * 32 + row_l] = m_run[mf][i];
                lpart[pbase * 32 + row_l] = lpp[mf][i];
            }
        }
}

// ---------------- flash merge: combine <=4 bf16 partials per (bh,strip) -> bf16 y ----------------
__global__ __launch_bounds__(256)
void k_flash_merge(const unsigned short* __restrict__ opart, const float* __restrict__ mpart,
                   const float* __restrict__ lpart, unsigned short* __restrict__ yout) {
    int bs = blockIdx.x;
    int bh = bs >> 6, strip = bs & 63;
    int b = bh >> 4, h = bh & 15;
    int np, base;
    if (strip < 16)      { np = 1; base = strip; }
    else if (strip < 32) { np = 2; base = 16 + (strip - 16) * 2; }
    else if (strip < 48) { np = 3; base = 48 + (strip - 32) * 3; }
    else                 { np = 4; base = 96 + (strip - 48) * 4; }
    long p0 = (long)(bh * 160 + base);
    int tid = threadIdx.x;
    int r = tid >> 3, c0 = (tid & 7) * 8;
    float M = -3.0e38f;
    for (int p = 0; p < np; ++p) M = fmaxf(M, mpart[(p0 + p) * 32 + r]);
    float L = 0.f;
    float acc[8] = {};
    for (int p = 0; p < np; ++p) {
        float sc = __expf(mpart[(p0 + p) * 32 + r] - M);
        L += lpart[(p0 + p) * 32 + r] * sc;
        const unsigned short* op = opart + (p0 + p) * 2048 + r * 64 + c0;
        ushort4 a = *(const ushort4*)op;
        ushort4 bq = *(const ushort4*)(op + 4);
        acc[0] += bu2f(a.x) * sc; acc[1] += bu2f(a.y) * sc;
        acc[2] += bu2f(a.z) * sc; acc[3] += bu2f(a.w) * sc;
        acc[4] += bu2f(bq.x) * sc; acc[5] += bu2f(bq.y) * sc;
        acc[6] += bu2f(bq.z) * sc; acc[7] += bu2f(bq.w) * sc;
    }
    float inv = 1.0f / L;
    long row = (long)b * Tc + strip * 32 + r;
    unsigned short* yp = yout + row * 1024 + h * 64 + c0;
    ushort4 o1, o2;
    o1.x = f2bu(acc[0] * inv); o1.y = f2bu(acc[1] * inv); o1.z = f2bu(acc[2] * inv); o1.w = f2bu(acc[3] * inv);
    o2.x = f2bu(acc[4] * inv); o2.y = f2bu(acc[5] * inv); o2.z = f2bu(acc[6] * inv); o2.w = f2bu(acc[7] * inv);
    *(ushort4*)yp = o1;
    *(ushort4*)(yp + 4) = o2;
}

// ---------------- AFT gated cumsum (bf16 qkv): 3-pass chunked ----------------
__global__ void k_aft_p1(const unsigned short* __restrict__ qkv, float* __restrict__ cw, float* __restrict__ cs) {
    int id = blockIdx.x * TPB + threadIdx.x;
    int bc = id & 2047, ch = id >> 11;
    int b = bc >> 10, c = bc & 1023;
    const unsigned short* base = qkv + ((long)(b * Tc + ch * CHL)) * 3072 + c;
    float sw = 0.f, sv = 0.f;
    for (int i = 0; i < CHL; ++i) {
        float k = bu2f(base[1024]), v = bu2f(base[2048]);
        float e = __expf(k);
        sw += e; sv += e * v;
        base += 3072;
    }
    cw[ch * 2048 + bc] = sw; cs[ch * 2048 + bc] = sv;
}

__global__ void k_aft_p2(float* __restrict__ cw, float* __restrict__ cs) {
    int bc = blockIdx.x * TPB + threadIdx.x;
    float rw = 0.f, rv = 0.f;
    for (int ch = 0; ch < NCH; ++ch) {
        long idx = (long)ch * 2048 + bc;
        float tw = cw[idx], tv = cs[idx];
        cw[idx] = rw; cs[idx] = rv; rw += tw; rv += tv;
    }
}

__global__ void k_aft_p3(const unsigned short* __restrict__ qkv, const float* __restrict__ cw,
                         const float* __restrict__ cs, unsigned short* __restrict__ y) {
    int id = blockIdx.x * TPB + threadIdx.x;
    int bc = id & 2047, ch = id >> 11;
    int b = bc >> 10, c = bc & 1023;
    float aw = cw[ch * 2048 + bc], av = cs[ch * 2048 + bc];
    long t0 = (long)b * Tc + ch * CHL;
    const unsigned short* base = qkv + t0 * 3072 + c;
    unsigned short* yp = y + t0 * 1024 + c;
    for (int i = 0; i < CHL; ++i) {
        float q = bu2f(base[0]), k = bu2f(base[1024]), v = bu2f(base[2048]);
        float e = __expf(k);
        av += e * v; aw += e;
        float sig = 1.0f / (1.0f + __expf(-q));
        yp[0] = f2bu(sig * av / (aw + 1e-6f));
        base += 3072; yp += 1024;
    }
}

// ---------------- fused u*silu(v) -> bf16 + rowrms(u), bf16 uv in (block per row) ----------------
__global__ void k_silu_rms(const unsigned short* __restrict__ uv, unsigned short* __restrict__ g,
                           float* __restrict__ rs) {
    __shared__ float red[TPB];
    long row = blockIdx.x;
    const unsigned short* up = uv + row * 2048;
    ushort4 u4 = *(const ushort4*)(up + threadIdx.x * 4);
    ushort4 v4 = *(const ushort4*)(up + 1024 + threadIdx.x * 4);
    float u0 = bu2f(u4.x), u1 = bu2f(u4.y), u2 = bu2f(u4.z), u3 = bu2f(u4.w);
    float v0 = bu2f(v4.x), v1 = bu2f(v4.y), v2 = bu2f(v4.z), v3 = bu2f(v4.w);
    ushort4 o;
    o.x = f2bu(u0 * v0 / (1.f + __expf(-v0)));
    o.y = f2bu(u1 * v1 / (1.f + __expf(-v1)));
    o.z = f2bu(u2 * v2 / (1.f + __expf(-v2)));
    o.w = f2bu(u3 * v3 / (1.f + __expf(-v3)));
    *(ushort4*)(g + row * 1024 + threadIdx.x * 4) = o;
    red[threadIdx.x] = u0 * u0 + u1 * u1 + u2 * u2 + u3 * u3;
    __syncthreads();
    for (int off = 128; off > 0; off >>= 1) {
        if (threadIdx.x < off) red[threadIdx.x] += red[threadIdx.x + off];
        __syncthreads();
    }
    if (threadIdx.x == 0) rs[row] = rsqrtf(red[0] / 1024.0f + F32_EPS);
}

// ---------------- u * silu(v) -> bf16 (final swiglu, bf16 in) ----------------
__global__ void k_silu_gate(const unsigned short* __restrict__ uv, unsigned short* __restrict__ g, long n4) {
    long i = (long)blockIdx.x * TPB + threadIdx.x;
    if (i >= n4) return;
    long r = i >> 8, c4 = i & 255;
    ushort4 u4 = *(const ushort4*)(uv + r * 2048 + c4 * 4);
    ushort4 v4 = *(const ushort4*)(uv + r * 2048 + 1024 + c4 * 4);
    float u0 = bu2f(u4.x), u1 = bu2f(u4.y), u2 = bu2f(u4.z), u3 = bu2f(u4.w);
    float v0 = bu2f(v4.x), v1 = bu2f(v4.y), v2 = bu2f(v4.z), v3 = bu2f(v4.w);
    ushort4 o;
    o.x = f2bu(u0 * v0 / (1.f + __expf(-v0)));
    o.y = f2bu(u1 * v1 / (1.f + __expf(-v1)));
    o.z = f2bu(u2 * v2 / (1.f + __expf(-v2)));
    o.w = f2bu(u3 * v3 / (1.f + __expf(-v3)));
    *(ushort4*)(g + r * 1024 + c4 * 4) = o;
}

// ---------------- w_out = (slab0+slab1)*s*silu(w_in) + w_in  (also emits bf16 copy) ----------------
__global__ void k_wupdate(float* __restrict__ wout, const float* __restrict__ win,
                          const unsigned short* __restrict__ p0, const unsigned short* __restrict__ p1,
                          const float* __restrict__ scale, unsigned short* __restrict__ wb, long n4) {
    long i = (long)blockIdx.x * TPB + threadIdx.x;
    if (i >= n4) return;
    float s = scale[0];
    float4 wv = *(const float4*)(win + i * 4);
    ushort4 a = *(const ushort4*)(p0 + i * 4);
    ushort4 b = *(const ushort4*)(p1 + i * 4);
    float p0f = bu2f(a.x) + bu2f(b.x), p1f = bu2f(a.y) + bu2f(b.y);
    float p2f = bu2f(a.z) + bu2f(b.z), p3f = bu2f(a.w) + bu2f(b.w);
    float4 o;
    o.x = p0f * s * (wv.x / (1.f + __expf(-wv.x))) + wv.x;
    o.y = p1f * s * (wv.y / (1.f + __expf(-wv.y))) + wv.y;
    o.z = p2f * s * (wv.z / (1.f + __expf(-wv.z))) + wv.z;
    o.w = p3f * s * (wv.w / (1.f + __expf(-wv.w))) + wv.w;
    *(float4*)(wout + i * 4) = o;
    ushort4 ob; ob.x = f2bu(o.x); ob.y = f2bu(o.y); ob.z = f2bu(o.z); ob.w = f2bu(o.w);
    *(ushort4*)(wb + i * 4) = ob;
}

// ---------------- 8-slab reduce + scale + row softmax -> fp32 out ----------------
__global__ void k_softmax8(const float* __restrict__ parts, float* __restrict__ outb, float fscale) {
    __shared__ float red[TPB];
    __shared__ float rowbuf[1024];
    long row = blockIdx.x;
    const float* p0 = parts + row * 1024;
    for (int c = threadIdx.x; c < 1024; c += TPB) {
        float v = 0.f;
        #pragma unroll
        for (int sIdx = 0; sIdx < 8; ++sIdx) v += p0[c + (long)sIdx * 1048576];
        rowbuf[c] = v * fscale;
    }
    __syncthreads();
    float m = -3.0e38f;
    for (int c = threadIdx.x; c < 1024; c += TPB) m = fmaxf(m, rowbuf[c]);
    red[threadIdx.x] = m; __syncthreads();
    for (int o = 128; o > 0; o >>= 1) {
        if (threadIdx.x < o) red[threadIdx.x] = fmaxf(red[threadIdx.x], red[threadIdx.x + o]);
        __syncthreads();
    }
    m = red[0]; __syncthreads();
    float sum = 0.f;
    for (int c = threadIdx.x; c < 1024; c += TPB) sum += __expf(rowbuf[c] - m);
    red[threadIdx.x] = sum; __syncthreads();
    for (int o = 128; o > 0; o >>= 1) {
        if (threadIdx.x < o) red[threadIdx.x] += red[threadIdx.x + o];
        __syncthreads();
    }
    float inv = 1.0f / red[0];
    for (int c = threadIdx.x; c < 1024; c += TPB)
        outb[row * 1024 + c] = __expf(rowbuf[c] - m) * inv;
}

// ---------------- tea: rotary + per-head rmsnorm + split, bf16 in/out ----------------
__global__ void k_rot_split(const unsigned short* __restrict__ qkvp, const float* __restrict__ cosp,
                            const float* __restrict__ sinp, unsigned short* __restrict__ hq,
                            unsigned short* __restrict__ hk, unsigned short* __restrict__ hv) {
    __shared__ float row[3072];
    __shared__ float cs[32], sn[32];
    int bt = blockIdx.x;
    int b = bt >> 11, t = bt & 2047;
    const unsigned short* src = qkvp + (long)bt * 3072;
    #pragma unroll
    for (int u = 0; u < 3; ++u) {
        int idx = threadIdx.x + u * 256;
        ushort4 v = *(const ushort4*)(src + idx * 4);
        row[idx * 4 + 0] = bu2f(v.x); row[idx * 4 + 1] = bu2f(v.y);
        row[idx * 4 + 2] = bu2f(v.z); row[idx * 4 + 3] = bu2f(v.w);
    }
    if (threadIdx.x < 32) { cs[threadIdx.x] = cosp[t * 32 + threadIdx.x]; sn[threadIdx.x] = sinp[t * 32 + threadIdx.x]; }
    __syncthreads();
    int h = threadIdx.x >> 4, li = threadIdx.x & 15;
    int base = h * 192;
    long obase = ((long)(b * Hc + h) * Tc + t) * 64 + li * 4;
    {
        float r[4]; float ss = 0.f;
        #pragma unroll
        for (int j = 0; j < 4; ++j) {
            int d = li * 4 + j;
            float val = (d < 32) ? (row[base + d] * cs[d] + row[base + d + 32] * sn[d])
                                 : (-row[base + d - 32] * sn[d - 32] + row[base + d] * cs[d - 32]);
            r[j] = val; ss += val * val;
        }
        ss = sum16(ss);
        float sc = rsqrtf(ss / 64.0f + F32_EPS);
        ushort4 o; o.x = f2bu(r[0] * sc); o.y = f2bu(r[1] * sc); o.z = f2bu(r[2] * sc); o.w = f2bu(r[3] * sc);
        *(ushort4*)(hq + obase) = o;
    }
    {
        int kb = base + 64;
        float r[4]; float ss = 0.f;
        #pragma unroll
        for (int j = 0; j < 4; ++j) {
            int d = li * 4 + j;
            float val = (d < 32) ? (row[kb + d] * cs[d] + row[kb + d + 32] * sn[d])
                                 : (-row[kb + d - 32] * sn[d - 32] + row[kb + d] * cs[d - 32]);
            r[j] = val; ss += val * val;
        }
        ss = sum16(ss);
        float sc = rsqrtf(ss / 64.0f + F32_EPS);
        ushort4 o; o.x = f2bu(r[0] * sc); o.y = f2bu(r[1] * sc); o.z = f2bu(r[2] * sc); o.w = f2bu(r[3] * sc);
        *(ushort4*)(hk + obase) = o;
    }
    {
        ushort4 o;
        o.x = f2bu(row[base + 128 + li * 4 + 0]); o.y = f2bu(row[base + 128 + li * 4 + 1]);
        o.z = f2bu(row[base + 128 + li * 4 + 2]); o.w = f2bu(row[base + 128 + li * 4 + 3]);
        *(ushort4*)(hv + obase) = o;
    }
}

extern "C" void kernel_launch(void* const* d_in, const int* in_sizes, int n_in,
                              void* d_out, int out_size, void* d_ws, size_t ws_size,
                              hipStream_t stream) {
    const float* x_in = (const float*)d_in[0];
    const float* w_in = (const float*)d_in[1];
    const float* cos_in = (const float*)d_in[2];
    const float* sin_in = (const float*)d_in[3];
    float* out = (float*)d_out;
    float* ws = (float*)d_ws;

    long off = 0;
    float* w_cur = ws + off;  off += (long)WR * Ec;
    float* w_tmp = ws + off;  off += (long)WR * Ec;   // mostly unused now (kept for layout stability)
    float* xbuf  = ws + off;  off += BT * Ec;
    float* R     = ws + off;  off += BT * 3L * QKVc;  // bf16 qkvb+uvb | oa fp32 slabs | bf16 opart | split slabs
    float* oab   = ws + off;  off += (long)Ec * Ec;   // also: flash m/l partials
    float* red   = ws + off;  off += 16384;
    float* scales= ws + off;  off += 16;
    float* uscale= ws + off;  off += 4096;
    float* chw   = ws + off;  off += 2048L * NCH;
    float* chs   = ws + off;  off += 2048L * NCH;
    unsigned short* qkvb  = (unsigned short*)R;          // 12.58M ushorts
    unsigned short* uvb   = qkvb + 12582912L;            // 8.39M ushorts
    unsigned short* opartb= qkvb;                         // final-phase alias
    unsigned short* wsplit = qkvb;                        // w@oa split slabs (2 x 6.29M)
    unsigned short* osplit = uvb;                         // out-proj split slabs (2 x 4.19M)
    float* oaparts = R;                                   // oa split-K x8 fp32 slabs (8 x 1M floats)
    float* mpart = oab;
    float* lpart = oab + 5120L * 32;

    unsigned short* bp = (unsigned short*)(ws + off);
    long bo = 0;
    unsigned short* wb  = bp + bo; bo += (long)WR * Ec;
    unsigned short* xbn = bp + bo; bo += BT * Ec;
    unsigned short* ybn = bp + bo; bo += BT * Ec;
    unsigned short* gbn = bp + bo; bo += BT * Ec;
    unsigned short* t1  = bp + bo; bo += BT * Ec;            // o^T | hq
    unsigned short* t2  = bp + bo; bo += BT * Ec;            // v^T | hk
    unsigned short* t3  = bp + bo; bo += BT * Ec;            // oa^T | hvS
    unsigned short* t4  = bp + bo; bo += BT * Ec;            // hvT

    const float rsWR = 1.0f / sqrtf(6144.0f);
    const long wsw = 3072L * 1024, wout = 5120L * 1024;

    // one-time bf16 copy of w (from input)
    k_cast_bf16<<<(int)(((long)WR * Ec / 4) / TPB), TPB, 0, stream>>>(w_in, wb, (long)WR * Ec / 4);
    // layer 0's rmsnorm of x_in (later layers get xbn from the fused merge)
    k_rms1024b<<<BT, TPB, 0, stream>>>(x_in, xbn, 1024, 1024);

    for (int layer = 0; layer < 2; ++layer) {
        const float* wsrc = layer == 0 ? w_in : w_cur;   // fp32 weights
        const float* xsrc = layer == 0 ? x_in : xbuf;    // fp32 activations (residual)
        k_std_partial3<<<dim3(256, 3), TPB, 0, stream>>>(wsrc, red);
        k_std_final3<<<1, TPB, 0, stream>>>(red, scales);
        k_bgemm<1><<<dim3(24, 32, 1), TPB, 0, stream>>>(
            1024, xbn, 1024, 0, wb, 1024, 0, qkvb, 3072, 0, 0, 1, scales + 0, 1.0f, nullptr, 0);
        k_rms_qk<<<8192, TPB, 0, stream>>>(qkvb);
        k_aft_p1<<<(2048 * NCH) / TPB, TPB, 0, stream>>>(qkvb, chw, chs);
        k_aft_p2<<<2048 / TPB, TPB, 0, stream>>>(chw, chs);
        k_aft_p3<<<(2048 * NCH) / TPB, TPB, 0, stream>>>(qkvb, chw, chs, ybn);
        k_bgemm<1><<<dim3(16, 32, 1), TPB, 0, stream>>>(
            1024, ybn, 1024, 0, wb + wsw, 1024, 0, uvb, 2048, 0, 0, 1, scales + 1, 1.0f, nullptr, 0);
        k_silu_rms<<<BT, TPB, 0, stream>>>(uvb, gbn, uscale);
        k_tcast2<<<dim3(16, 64, 2), TPB, 0, stream>>>(uvb, uscale, t1, t2);
        // oa = softmax(o^T @ a * E^-0.5), split-K x8 into fp32 slabs (qkvb/uvb regions dead)
        k_bgemm<0><<<dim3(8, 8, 8), TPB, 0, stream>>>(
            512, t1, 4096, 0, t2, 4096, 0, oaparts, 1024, 0, 1048576L, 8, nullptr, 1.0f, nullptr, 0);
        k_softmax8<<<1024, TPB, 0, stream>>>(oaparts, oab, 0.03125f);
        k_tcast<float><<<dim3(16, 16, 1), TPB, 0, stream>>>(oab, 1024, 0, t3, 1024, 0, nullptr);
        // x' = x + g @ w_out^T * s2 : split-K x2 + fused merge+residual+rmsnorm
        k_bgemm<1><<<dim3(8, 32, 2), TPB, 0, stream>>>(
            512, gbn, 1024, 0, wb + wout, 1024, 0, osplit, 1024, 0, 4194304L, 2, scales + 2, 1.0f, nullptr, 0);
        k_merge2rms<<<BT, TPB, 0, stream>>>(osplit, osplit + 4194304L, xsrc, xbuf, xbn);
        // w@oa: split-K x2 slabs; stats from slabs; wupdate merges inline (no w_tmp pass)
        k_bgemm<1><<<dim3(8, 48, 2), TPB, 0, stream>>>(
            512, wb, 1024, 0, t3, 1024, 0, wsplit, 1024, 0, 6291456L, 2, nullptr, 1.0f, nullptr, 0);
        k_stat2<<<(int)(((long)WR * 1024 / 4) / TPB), TPB, 0, stream>>>(
            wsplit, wsplit + 6291456L, red);
        k_std_finalB<<<1, TPB, 0, stream>>>(red, (float)((long)WR * 1024), rsWR, scales + 3);
        k_wupdate<<<(int)(((long)WR * 1024 / 4) / TPB), TPB, 0, stream>>>(
            w_cur, wsrc, wsplit, wsplit + 6291456L, scales + 3, wb, (long)WR * 1024 / 4);
    }

    // -------- final tea (no w_norm); xbn already holds rmsnorm(x) from layer 1's merge --------
    k_bgemm<1><<<dim3(24, 32, 1), TPB, 0, stream>>>(
        1024, xbn, 1024, 0, wb, 1024, 0, qkvb, 3072, 0, 0, 1, nullptr, 1.0f, nullptr, 0);
    k_rot_split<<<BT, TPB, 0, stream>>>(qkvb, cos_in, sin_in, t1, t2, t3);
    k_tcast<unsigned short><<<dim3(1, 32, 32), TPB, 0, stream>>>(
        t3, 64, (long)Tc * 64, t4, 2048, (long)Tc * 64, nullptr);
    // flash-decoding: 5120 items in 1280 blocks (4 waves/block, independent), then merge
    k_flash_split<<<dim3(1280), TPB, 0, stream>>>(t1, t2, t4, opartb, mpart, lpart);
    k_flash_merge<<<dim3(2048), TPB, 0, stream>>>(opartb, mpart, lpart, ybn);
    // final swiglu -> d_out
    k_bgemm<1><<<dim3(16, 32, 1), TPB, 0, stream>>>(
        1024, ybn, 1024, 0, wb + wsw, 1024, 0, uvb, 2048, 0, 0, 1, nullptr, 1.0f, nullptr, 0);
    k_silu_gate<<<(int)((BT * 1024 / 4) / TPB), TPB, 0, stream>>>(uvb, gbn, BT * 1024 / 4);
    // final out-proj: split-K x2 into dead qkvb region + merge(+x residual) -> out
    k_bgemm<1><<<dim3(8, 32, 2), TPB, 0, stream>>>(
        512, gbn, 1024, 0, wb + wout, 1024, 0, qkvb, 1024, 0, 4194304L, 2, nullptr, 1.0f, nullptr, 0);
    k_merge2<<<(int)((BT * 1024 / 4) / TPB), TPB, 0, stream>>>(
        qkvb, qkvb + 4194304L, xbuf, out, BT * 1024 / 4);
}